// Round 2
// baseline (443.598 us; speedup 1.0000x reference)
//
#include <hip/hip_runtime.h>
#include <stdint.h>
#include <math.h>

#define N_ANCH   1000000
#define PRE_K    6000
#define POST_K   1000
#define WORDS    94            // ceil(6000/64) -> 6016 bit columns
#define ROWS     6016          // WORDS*64
#define W_IMG    1333.0f
#define H_IMG    800.0f
#define NBLK1    256           // histogram blocks (x1024 threads) — fill all 256 CUs

// radix sort config (single block)
#define NS       7168          // sort capacity (112 tiles of 64)
#define TILES    112
#define TPW      7             // tiles per wave (16 waves)
#define PASSES   13            // 13 x 4 bits = 52 = 32-bit key + 20-bit idx

// ws layout (bytes)
#define OFF_KEYS   0x000000u   // u32[1e6] = 4 MiB
#define OFF_HIST1  0x400000u   // u32[4096] global coarse hist (16 KiB)
#define OFF_HIST2  0x404000u   // u32[256]  global refine hist (1 KiB)
#define OFF_CTRL   0x410000u   // [0]=count [1]=T20 [2]=coarse c [3]=base [4],[5]=done ctrs
#define OFF_CAND   0x410100u   // u64[NS] 56 KiB
#define OFF_BOXES  0x41F000u   // float4[6016]
#define OFF_VALID  0x437000u   // u32[6016]
#define OFF_MASK   0x440000u   // u64[6016*94] row-major: mask[row*WORDS + w]

__device__ __forceinline__ float ref_exp(float v) {
  return (float)exp((double)v);   // correctly-rounded f32 exp via double
}

__device__ __forceinline__ void decode_box(float ax, float ay, float az, float aw,
                                           float dx, float dy, float dz, float dw,
                                           float& x1, float& y1, float& x2, float& y2,
                                           bool& valid) {
  // bit-exact replica of reference fp32 op order (no FMA contraction)
  float wa = __fsub_rn(az, ax);
  float ha = __fsub_rn(aw, ay);
  float xa = __fadd_rn(ax, __fmul_rn(0.5f, wa));
  float ya = __fadd_rn(ay, __fmul_rn(0.5f, ha));
  float x  = __fadd_rn(__fmul_rn(dx, wa), xa);
  float y  = __fadd_rn(__fmul_rn(dy, ha), ya);
  float w  = __fmul_rn(ref_exp(dz), wa);
  float h  = __fmul_rn(ref_exp(dw), ha);
  float hw = __fmul_rn(0.5f, w);
  float hh = __fmul_rn(0.5f, h);
  x1 = fminf(fmaxf(__fsub_rn(x, hw), 0.0f), W_IMG - 1.0f);
  y1 = fminf(fmaxf(__fsub_rn(y, hh), 0.0f), H_IMG - 1.0f);
  x2 = fminf(fmaxf(__fadd_rn(x, hw), 0.0f), W_IMG - 1.0f);
  y2 = fminf(fmaxf(__fadd_rn(y, hh), 0.0f), H_IMG - 1.0f);
  valid = (__fsub_rn(x2, x1) >= 16.0f) && (__fsub_rn(y2, y1) >= 16.0f);
}

__device__ __forceinline__ uint32_t wave_iscan(uint32_t x, int lane) {
  #pragma unroll
  for (int off = 1; off < 64; off <<= 1) {
    uint32_t u = __shfl_up(x, off, 64);
    if (lane >= off) x += u;
  }
  return x;
}

// ---- K1: fast f32 validity filter + logit-bit key + 12-bit hist; last block finds coarse cut ----
// Sigmoid is strictly monotone in the logit -> selection/cut can key on raw logit
// bits (one XOR). Exact f32 sigmoid keys (needed only for tie ORDERING) are
// computed later in k_sortgather for the <=7168 candidates. Validity uses an
// __expf f32 decode with a conservative 0.02 margin around the 16.0 threshold;
// only borderline anchors (~1e-4 of them) take the exact f64 path.
__global__ void __launch_bounds__(1024) k_score(const float4* __restrict__ anchors,
                                                const float4* __restrict__ deltas,
                                                const float*  __restrict__ logits,
                                                uint32_t* __restrict__ keys,
                                                uint32_t* __restrict__ hist1,
                                                uint32_t* __restrict__ ctrl) {
  __shared__ uint32_t lh[4096];
  __shared__ uint32_t amLast;
  int tid = threadIdx.x;
  int lane = tid & 63;
  for (int b = tid; b < 4096; b += 1024) lh[b] = 0u;
  __syncthreads();
  for (int i = blockIdx.x * 1024 + tid; i < N_ANCH; i += NBLK1 * 1024) {
    float4 a = anchors[i];
    float4 d = deltas[i];
    // fast f32 decode (filter only; exact op order irrelevant under margin)
    float wa = a.z - a.x, ha = a.w - a.y;
    float xa = a.x + 0.5f * wa, ya = a.y + 0.5f * ha;
    float x = d.x * wa + xa, y = d.y * ha + ya;
    float w = __expf(d.z) * wa, h = __expf(d.w) * ha;
    float fx1 = fminf(fmaxf(x - 0.5f * w, 0.0f), W_IMG - 1.0f);
    float fx2 = fminf(fmaxf(x + 0.5f * w, 0.0f), W_IMG - 1.0f);
    float fy1 = fminf(fmaxf(y - 0.5f * h, 0.0f), H_IMG - 1.0f);
    float fy2 = fminf(fmaxf(y + 0.5f * h, 0.0f), H_IMG - 1.0f);
    float X = fx2 - fx1, Y = fy2 - fy1;
    bool valid = (X >= 16.0f) && (Y >= 16.0f);
    if (fabsf(X - 16.0f) < 0.02f || fabsf(Y - 16.0f) < 0.02f) {
      float ex1, ey1, ex2, ey2; bool vv;      // borderline: exact f64 recheck (rare)
      decode_box(a.x, a.y, a.z, a.w, d.x, d.y, d.z, d.w, ex1, ey1, ex2, ey2, vv);
      valid = vv;
    }
    uint32_t u = __float_as_uint(logits[i]);
    uint32_t o = (u & 0x80000000u) ? ~u : (u | 0x80000000u);  // ascending in logit
    uint32_t kd = valid ? ~o : 0xFFFFFFFFu;                   // ascending key = descending logit
    keys[i] = kd;
    // ballot-aggregate the hot invalid bin (4095): one LDS atomic per wave
    uint64_t invb = __ballot(!valid);
    if (valid) {
      atomicAdd(&lh[kd >> 20], 1u);
    } else if ((invb & ((1ull << lane) - 1ull)) == 0ull) {
      atomicAdd(&lh[4095], (uint32_t)__popcll((unsigned long long)invb));
    }
  }
  __syncthreads();
  // sparse flush: populated bins only -> few hundred atomics/block
  for (int b = tid; b < 4096; b += 1024) {
    uint32_t c = lh[b];
    if (c) atomicAdd(&hist1[b], c);
  }
  __threadfence();
  if (tid == 0) amLast = (atomicAdd(&ctrl[4], 1u) == NBLK1 - 1) ? 1u : 0u;
  __syncthreads();
  if (!amLast) return;
  // ---- findcut1 (this block only): scan 16 KB global hist ----
  __threadfence();
  __shared__ uint32_t part[1024];
  int t = tid;
  const uint4* h4 = (const uint4*)hist1;
  uint4 s4 = h4[t];                          // thread t owns bins 4t..4t+3
  uint32_t tot = s4.x + s4.y + s4.z + s4.w;
  part[t] = tot;
  __syncthreads();
  uint32_t inc = tot;
  for (int off = 1; off < 1024; off <<= 1) {
    uint32_t u2 = (t >= off) ? part[t - off] : 0u;
    __syncthreads();
    inc += u2;
    part[t] = inc;
    __syncthreads();
  }
  uint32_t ex = inc - tot;
  if (ex < PRE_K && inc >= PRE_K) {
    uint32_t run = ex;
    uint32_t binv[4] = { s4.x, s4.y, s4.z, s4.w };
    for (int b = 0; b < 4; b++) {
      if (run + binv[b] >= PRE_K) { ctrl[2] = 4 * t + b; ctrl[3] = run; break; }
      run += binv[b];
    }
  }
  if (t == 1023 && inc < PRE_K) { ctrl[2] = 4095u; ctrl[3] = inc; }
}

// ---- K2: refine next 8 bits in coarse bin; last block finds T20 ----
__global__ void __launch_bounds__(1024) k_hist2(const uint32_t* __restrict__ keys,
                                                uint32_t* __restrict__ ctrl,
                                                uint32_t* __restrict__ hist2) {
  __shared__ uint32_t lh[256];
  __shared__ uint32_t amLast;
  int tid = threadIdx.x;
  if (tid < 256) lh[tid] = 0u;
  __syncthreads();
  uint32_t c = ctrl[2];
  for (int i = blockIdx.x * 1024 + tid; i < N_ANCH; i += NBLK1 * 1024) {
    uint32_t k = keys[i];
    if ((k >> 20) == c) atomicAdd(&lh[(k >> 12) & 0xFFu], 1u);
  }
  __syncthreads();
  if (tid < 256) {
    uint32_t v = lh[tid];
    if (v) atomicAdd(&hist2[tid], v);
  }
  __threadfence();
  if (tid == 0) amLast = (atomicAdd(&ctrl[5], 1u) == NBLK1 - 1) ? 1u : 0u;
  __syncthreads();
  if (!amLast) return;
  __threadfence();
  // ---- findcut2: single wave, lane owns 4 sub-bins ----
  if (tid < 64) {
    int lane = tid;
    const uint32_t* p = hist2 + 4 * lane;
    uint32_t b0 = p[0], b1 = p[1], b2 = p[2], b3 = p[3];
    uint32_t tot = b0 + b1 + b2 + b3;
    uint32_t inc = wave_iscan(tot, lane);
    uint32_t base = ctrl[3];
    uint32_t ex = inc - tot;
    if (base + ex < PRE_K && base + inc >= PRE_K) {
      uint32_t run = base + ex;
      uint32_t binv[4] = { b0, b1, b2, b3 };
      for (int b = 0; b < 4; b++) {
        if (run + binv[b] >= PRE_K) { ctrl[1] = (c << 8) | (uint32_t)(4 * lane + b); break; }
        run += binv[b];
      }
    }
    if (lane == 63 && base + inc < PRE_K) ctrl[1] = 0xFFFFFu;  // take everything
  }
}

// ---- K3: compact candidates (key prefix <= T), wave-aggregated atomic ----
__global__ void k_compact(const uint32_t* __restrict__ keys,
                          const uint32_t* __restrict__ ctrl,
                          uint32_t* __restrict__ cnt,
                          uint64_t* __restrict__ cand) {
  int i = blockIdx.x * blockDim.x + threadIdx.x;
  uint32_t T = ctrl[1];
  bool pass = (i < N_ANCH) && ((keys[i] >> 12) <= T);
  uint64_t m = __ballot(pass);
  if (pass) {
    int lane = threadIdx.x & 63;
    int leader = __ffsll((unsigned long long)m) - 1;
    uint32_t base = 0;
    if (lane == leader) base = atomicAdd(cnt, (uint32_t)__popcll((unsigned long long)m));
    base = (uint32_t)__shfl((int)base, leader);
    uint32_t pos = (uint32_t)__popcll((unsigned long long)(m & ((1ull << lane) - 1ull)));
    uint32_t p = base + pos;
    if (p < NS) cand[p] = ((uint64_t)keys[i] << 20) | (uint32_t)i;  // 52-bit packed
  }
}

// ---- K4: re-key (exact sigmoid) + single-block LSD radix sort + gather/decode ----
__global__ void __launch_bounds__(1024) k_sortgather(
    const uint32_t* __restrict__ ctrl,
    const uint64_t* __restrict__ cand,
    const float*  __restrict__ logits,
    const float4* __restrict__ anchors,
    const float4* __restrict__ deltas,
    float4* __restrict__ boxes,
    uint32_t* __restrict__ valid) {
  __shared__ uint64_t buf[NS];            // 56 KiB
  __shared__ uint32_t hist[16 * TILES];   // 7 KiB   hist[d*TILES + t]
  __shared__ uint32_t dtot[16];
  __shared__ uint32_t dbase[16];
  __shared__ uint32_t skipf;
  int tid = threadIdx.x;
  int wave = tid >> 6, lane = tid & 63;
  uint32_t M = ctrl[0]; if (M > NS) M = NS;
  const uint64_t pad = 0xFFFFFFFFFFFFFull;        // 52-bit max: sorts last
  // fill + re-key: replace logit key with EXACT f32 sigmoid key (reference
  // tie semantics). Only <=7168 f64 sigmoids total.
  for (int i = tid; i < NS; i += 1024) {
    uint64_t v = pad;
    if (i < (int)M) {
      uint64_t kk = cand[i];
      uint32_t lk  = (uint32_t)(kk >> 20);
      uint32_t idx = (uint32_t)(kk & 0xFFFFFu);
      uint32_t skey;
      if (lk == 0xFFFFFFFFu) {
        skey = 0xFF800000u;                       // invalid -> -inf key
      } else {
        double xd = (double)logits[idx];
        float s = (float)(1.0 / (1.0 + exp(-xd)));
        skey = 0x7FFFFFFFu & ~__float_as_uint(s); // descending-score -> ascending key
      }
      v = ((uint64_t)skey << 20) | idx;
    }
    buf[i] = v;
  }
  __syncthreads();
  uint64_t lmask_lt = (1ull << lane) - 1ull;

  for (int p = 0; p < PASSES; p++) {
    int shift = 4 * p;
    for (int i = tid; i < 16 * TILES; i += 1024) hist[i] = 0u;
    uint64_t v[TPW]; int dg[TPW]; int rk[TPW];
    #pragma unroll
    for (int k = 0; k < TPW; k++)
      v[k] = buf[(wave * TPW + k) * 64 + lane];
    __syncthreads();                       // B1: hist zeroed, all elements read
    #pragma unroll
    for (int k = 0; k < TPW; k++) {
      int d = (int)((v[k] >> shift) & 0xF);
      uint64_t m = ~0ull;
      #pragma unroll
      for (int b = 0; b < 4; b++) {
        uint64_t bal = __ballot((d >> b) & 1);
        m &= ((d >> b) & 1) ? bal : ~bal;
      }
      int r = (int)__popcll((unsigned long long)(m & lmask_lt));
      dg[k] = d; rk[k] = r;
      if (r == 0) hist[d * TILES + wave * TPW + k] = (uint32_t)__popcll((unsigned long long)m);
    }
    __syncthreads();                       // B2: hist counts complete
    {                                      // per-digit tile scan: wave w owns digit w
      int d = wave;
      uint32_t c0 = hist[d * TILES + lane];
      uint32_t c1 = (lane < TILES - 64) ? hist[d * TILES + 64 + lane] : 0u;
      uint32_t s0 = wave_iscan(c0, lane);
      uint32_t T0 = (uint32_t)__shfl((int)s0, 63, 64);
      uint32_t s1 = wave_iscan(c1, lane);
      uint32_t T1 = (uint32_t)__shfl((int)s1, 63, 64);
      hist[d * TILES + lane] = s0 - c0;
      if (lane < TILES - 64) hist[d * TILES + 64 + lane] = T0 + (s1 - c1);
      if (lane == 0) dtot[d] = T0 + T1;
    }
    __syncthreads();                       // B3
    if (wave == 0) {
      uint32_t x = (lane < 16) ? dtot[lane] : 0u;
      uint32_t xs = wave_iscan(x, lane);
      if (lane < 16) dbase[lane] = xs - x;
      if (lane == 0) skipf = 0u;
      if (lane < 16 && x == NS) skipf = 1u;   // single-digit pass -> identity scatter
    }
    __syncthreads();                       // B4
    if (!skipf) {
      #pragma unroll
      for (int k = 0; k < TPW; k++) {
        uint32_t dst = dbase[dg[k]] + hist[dg[k] * TILES + wave * TPW + k] + (uint32_t)rk[k];
        buf[dst] = v[k];
      }
    }
    __syncthreads();                       // B5
  }

  // ---- gather + decode epilogue (exact f64-exp decode, 6000 boxes) ----
  for (int r = tid; r < ROWS; r += 1024) {
    if (r >= PRE_K) { boxes[r] = make_float4(0.f, 0.f, 0.f, 0.f); valid[r] = 0u; continue; }
    uint64_t kk = buf[r];
    uint32_t kd = (uint32_t)(kk >> 20);
    if (kk >= pad || kd >= 0xFF800000u) {
      boxes[r] = make_float4(0.f, 0.f, 0.f, 0.f); valid[r] = 0u; continue;
    }
    uint32_t idx = (uint32_t)(kk & 0xFFFFFu);
    float4 a = anchors[idx];
    float4 d = deltas[idx];
    float x1, y1, x2, y2; bool vv;
    decode_box(a.x, a.y, a.z, a.w, d.x, d.y, d.z, d.w, x1, y1, x2, y2, vv);
    boxes[r] = make_float4(x1, y1, x2, y2);
    valid[r] = 1u;
  }
}

// ---- K5: IoU bitmask matrix, row-major mask[row*WORDS + w] ----
__global__ void __launch_bounds__(64) k_iou(const float4* __restrict__ boxes,
                                            uint64_t* __restrict__ mask) {
  int by = blockIdx.y, bx = blockIdx.x;
  if (bx < by) return;               // only words w >= row's group are ever read
  __shared__ float4 cb[64];
  int t = threadIdx.x;
  cb[t] = boxes[bx * 64 + t];
  __syncthreads();
  int i = by * 64 + t;
  float4 b = boxes[i];
  float ax1 = b.x, ay1 = b.y, ax2 = b.z, ay2 = b.w;
  float areaA = __fmul_rn(__fsub_rn(ax2, ax1), __fsub_rn(ay2, ay1));
  uint64_t bits = 0;
  for (int c = 0; c < 64; c++) {
    float4 o = cb[c];
    float areaB = __fmul_rn(__fsub_rn(o.z, o.x), __fsub_rn(o.w, o.y));
    float ix1 = fmaxf(ax1, o.x), iy1 = fmaxf(ay1, o.y);
    float ix2 = fminf(ax2, o.z), iy2 = fminf(ay2, o.w);
    float iw = fmaxf(__fsub_rn(ix2, ix1), 0.0f);
    float ih = fmaxf(__fsub_rn(iy2, iy1), 0.0f);
    float inter = __fmul_rn(iw, ih);
    float uni = __fsub_rn(__fadd_rn(areaA, areaB), inter);
    bool sup = (uni > 0.0f) && (__fdiv_rn(inter, uni) > 0.7f);
    bits |= ((uint64_t)sup) << c;
  }
  mask[(size_t)i * WORDS + bx] = bits;
}

// wave-uniform 64-bit broadcast via v_readlane
__device__ __forceinline__ uint64_t bcast64(uint64_t v, int lane) {
  uint32_t lo = (uint32_t)__builtin_amdgcn_readlane((int)(uint32_t)v, lane);
  uint32_t hi = (uint32_t)__builtin_amdgcn_readlane((int)(uint32_t)(v >> 32), lane);
  return ((uint64_t)hi << 32) | lo;
}

// ---- K6: sequential NMS scan, single wave ----
// Branch-free 64-step decision chain (wave-uniform SALU ops) + unconditional
// whole-group row loads issued before the chain, drained after -> latency
// hidden. __launch_bounds__(64,1): single wave, full VGPR budget.
__global__ void __launch_bounds__(64, 1) k_nms(const uint64_t* __restrict__ mask,
                                               const float4* __restrict__ boxes,
                                               const uint32_t* __restrict__ valid,
                                               float* __restrict__ out) {
  __shared__ uint32_t list[1088];     // cnt(<1000) + up to 64 per group
  int lane = threadIdx.x;
  int wp = (2 * lane < WORDS) ? 2 * lane : 0;  // word pair owned (lanes 47..63 clamped, never read)
  uint64_t rA = 0, rB = 0;            // removed-bit words 2*lane, 2*lane+1
  int cnt = 0;
  uint64_t colv = mask[(size_t)lane * WORDS + 0];     // prefetch group 0 diag
  uint32_t vf = valid[lane];
  for (int g = 0; g < WORDS; g++) {
    int base = g * 64;
    // ---- issue full-group row loads; drained at the fold below ----
    uint64_t vA[64], vB[64];
    #pragma unroll
    for (int r = 0; r < 64; r++) {
      ulonglong2 t2 = *(const ulonglong2*)(mask + (size_t)(base + r) * WORDS + wp);
      vA[r] = t2.x; vB[r] = t2.y;
    }
    uint64_t colv_c = colv;
    uint32_t vf_c = vf;
    if (g + 1 < WORDS) {                              // prefetch group g+1
      colv = mask[(size_t)(base + 64 + lane) * WORDS + (g + 1)];
      vf = valid[base + 64 + lane];
    }
    uint64_t cur = (g & 1) ? bcast64(rB, g >> 1) : bcast64(rA, g >> 1);
    uint64_t vmask = __ballot(vf_c != 0u);
    uint64_t alive = vmask & ~cur;
    // ---- branch-free sequential decision chain: 64 static steps ----
    uint64_t kept = 0;
    #pragma unroll
    for (int r = 0; r < 64; r++) {
      uint64_t mr = bcast64(colv_c, r);               // const-lane readlane, off critical path
      uint64_t take = (alive >> r) & 1ull;
      kept |= take << r;
      alive &= ~(take ? mr : 0ull);                   // diag bit clears r itself
    }
    // ---- record kept rows (parallel, rank by popcount) ----
    uint32_t below = (uint32_t)__popcll((unsigned long long)(kept & ((1ull << lane) - 1ull)));
    if ((kept >> lane) & 1ull) {
      uint32_t pos = (uint32_t)cnt + below;
      if (pos < 1088u) list[pos] = (uint32_t)(base + lane);
    }
    cnt += (int)__popcll((unsigned long long)kept);
    if (cnt >= POST_K) break;                         // later kept rows are dropped anyway
    if (g + 1 >= WORDS) break;
    // ---- fold: select-OR kept rows into removed words (drain happens here) ----
    uint64_t accA = 0, accB = 0;
    #pragma unroll
    for (int r = 0; r < 64; r++) {
      uint64_t s = 0ull - ((kept >> r) & 1ull);
      accA |= vA[r] & s;
      accB |= vB[r] & s;
    }
    rA |= accA;                                       // stale low words never re-read: no guard needed
    rB |= accB;
  }
  __syncthreads();
  float4* outv = (float4*)out;
  for (int k = lane; k < POST_K; k += 64)
    outv[k] = (k < cnt) ? boxes[list[k]] : make_float4(0.f, 0.f, 0.f, 0.f);
}

extern "C" void kernel_launch(void* const* d_in, const int* in_sizes, int n_in,
                              void* d_out, int out_size, void* d_ws, size_t ws_size,
                              hipStream_t stream) {
  const float4* anchors = (const float4*)d_in[1];
  const float4* deltas  = (const float4*)d_in[2];
  const float*  logits  = (const float*)d_in[3];
  char* w = (char*)d_ws;
  uint32_t* keys  = (uint32_t*)(w + OFF_KEYS);
  uint32_t* hist1 = (uint32_t*)(w + OFF_HIST1);
  uint32_t* hist2 = (uint32_t*)(w + OFF_HIST2);
  uint32_t* ctrl  = (uint32_t*)(w + OFF_CTRL);
  uint64_t* cand  = (uint64_t*)(w + OFF_CAND);
  float4*   boxes = (float4*)(w + OFF_BOXES);
  uint32_t* valid = (uint32_t*)(w + OFF_VALID);
  uint64_t* mask  = (uint64_t*)(w + OFF_MASK);
  float*    out   = (float*)d_out;

  hipMemsetAsync(w + OFF_HIST1, 0, 0x4400, stream);  // hist1 (16K) + hist2 (1K)
  hipMemsetAsync(w + OFF_CTRL, 0, 256, stream);      // counters only

  k_score<<<NBLK1, 1024, 0, stream>>>(anchors, deltas, logits, keys, hist1, ctrl);
  k_hist2<<<NBLK1, 1024, 0, stream>>>(keys, ctrl, hist2);
  k_compact<<<(N_ANCH + 255) / 256, 256, 0, stream>>>(keys, ctrl, &ctrl[0], cand);
  k_sortgather<<<1, 1024, 0, stream>>>(ctrl, cand, logits, anchors, deltas, boxes, valid);
  k_iou<<<dim3(WORDS, WORDS), 64, 0, stream>>>(boxes, mask);
  k_nms<<<1, 64, 0, stream>>>(mask, boxes, valid, out);
}

// Round 3
// 440.541 us; speedup vs baseline: 1.0069x; 1.0069x over previous
//
#include <hip/hip_runtime.h>
#include <stdint.h>
#include <math.h>

#define N_ANCH   1000000
#define PRE_K    6000
#define POST_K   1000
#define WORDS    94            // ceil(6000/64) -> 6016 bit columns
#define ROWS     6016          // WORDS*64
#define W_IMG    1333.0f
#define H_IMG    800.0f
#define NBLK1    256           // histogram blocks (x1024 threads)

// radix sort config (single block)
#define NS       7168          // sort capacity (112 tiles of 64)
#define TILES    112
#define TPW      7             // tiles per wave (16 waves)
#define PASSES   13            // 13 x 4 bits = 52 = 32-bit key + 20-bit idx

// ws layout (bytes)
#define OFF_KEYS   0x000000u   // u32[1e6] = 4 MiB
#define OFF_HIST1  0x400000u   // u32[4096] global coarse hist (16 KiB)
#define OFF_HIST2  0x404000u   // u32[256]  global refine hist (1 KiB)
#define OFF_CTRL   0x410000u   // [0]=count [1]=T20 [2]=coarse c [3]=base [4],[5]=done ctrs
#define OFF_CAND   0x410100u   // u64[NS] 56 KiB
#define OFF_BOXES  0x41F000u   // float4[6016]
#define OFF_VALID  0x437000u   // u32[6016]
#define OFF_MASK   0x440000u   // u64[6016*94] row-major: mask[row*WORDS + w]

__device__ __forceinline__ float ref_exp(float v) {
  return (float)exp((double)v);   // correctly-rounded f32 exp via double
}

__device__ __forceinline__ void decode_box(float ax, float ay, float az, float aw,
                                           float dx, float dy, float dz, float dw,
                                           float& x1, float& y1, float& x2, float& y2,
                                           bool& valid) {
  // bit-exact replica of reference fp32 op order (no FMA contraction)
  float wa = __fsub_rn(az, ax);
  float ha = __fsub_rn(aw, ay);
  float xa = __fadd_rn(ax, __fmul_rn(0.5f, wa));
  float ya = __fadd_rn(ay, __fmul_rn(0.5f, ha));
  float x  = __fadd_rn(__fmul_rn(dx, wa), xa);
  float y  = __fadd_rn(__fmul_rn(dy, ha), ya);
  float w  = __fmul_rn(ref_exp(dz), wa);
  float h  = __fmul_rn(ref_exp(dw), ha);
  float hw = __fmul_rn(0.5f, w);
  float hh = __fmul_rn(0.5f, h);
  x1 = fminf(fmaxf(__fsub_rn(x, hw), 0.0f), W_IMG - 1.0f);
  y1 = fminf(fmaxf(__fsub_rn(y, hh), 0.0f), H_IMG - 1.0f);
  x2 = fminf(fmaxf(__fadd_rn(x, hw), 0.0f), W_IMG - 1.0f);
  y2 = fminf(fmaxf(__fadd_rn(y, hh), 0.0f), H_IMG - 1.0f);
  valid = (__fsub_rn(x2, x1) >= 16.0f) && (__fsub_rn(y2, y1) >= 16.0f);
}

__device__ __forceinline__ uint32_t wave_iscan(uint32_t x, int lane) {
  #pragma unroll
  for (int off = 1; off < 64; off <<= 1) {
    uint32_t u = __shfl_up(x, off, 64);
    if (lane >= off) x += u;
  }
  return x;
}

// ---- K0: PURE streaming decode -> logit-bit key. No LDS, no atomics, no barriers.
// Diagnostic split: if this alone shows ~80 us, the streaming path is the cap;
// if it's fast, the histogram structure was the cost (see k_hist1).
__global__ void __launch_bounds__(256) k_decode(const float4* __restrict__ anchors,
                                                const float4* __restrict__ deltas,
                                                const float*  __restrict__ logits,
                                                uint32_t* __restrict__ keys) {
  int i = blockIdx.x * 256 + threadIdx.x;
  if (i >= N_ANCH) return;
  float4 a = anchors[i];
  float4 d = deltas[i];
  // fast f32 decode (filter only; exact op order irrelevant under margin)
  float wa = a.z - a.x, ha = a.w - a.y;
  float xa = a.x + 0.5f * wa, ya = a.y + 0.5f * ha;
  float x = d.x * wa + xa, y = d.y * ha + ya;
  float w = __expf(d.z) * wa, h = __expf(d.w) * ha;
  float fx1 = fminf(fmaxf(x - 0.5f * w, 0.0f), W_IMG - 1.0f);
  float fx2 = fminf(fmaxf(x + 0.5f * w, 0.0f), W_IMG - 1.0f);
  float fy1 = fminf(fmaxf(y - 0.5f * h, 0.0f), H_IMG - 1.0f);
  float fy2 = fminf(fmaxf(y + 0.5f * h, 0.0f), H_IMG - 1.0f);
  float X = fx2 - fx1, Y = fy2 - fy1;
  bool valid = (X >= 16.0f) && (Y >= 16.0f);
  if (fabsf(X - 16.0f) < 0.02f || fabsf(Y - 16.0f) < 0.02f) {
    float ex1, ey1, ex2, ey2; bool vv;      // borderline: exact f64 recheck (rare)
    decode_box(a.x, a.y, a.z, a.w, d.x, d.y, d.z, d.w, ex1, ey1, ex2, ey2, vv);
    valid = vv;
  }
  uint32_t u = __float_as_uint(logits[i]);
  uint32_t o = (u & 0x80000000u) ? ~u : (u | 0x80000000u);  // ascending in logit
  keys[i] = valid ? ~o : 0xFFFFFFFFu;                       // ascending key = descending logit
}

// ---- K1: 12-bit coarse hist over keys (4 MB read); last block finds coarse cut ----
__global__ void __launch_bounds__(1024) k_hist1(const uint32_t* __restrict__ keys,
                                                uint32_t* __restrict__ hist1,
                                                uint32_t* __restrict__ ctrl) {
  __shared__ uint32_t lh[4096];
  __shared__ uint32_t amLast;
  int tid = threadIdx.x;
  int lane = tid & 63;
  for (int b = tid; b < 4096; b += 1024) lh[b] = 0u;
  __syncthreads();
  for (int i = blockIdx.x * 1024 + tid; i < N_ANCH; i += NBLK1 * 1024) {
    uint32_t kd = keys[i];
    bool inv = (kd == 0xFFFFFFFFu);
    uint64_t invb = __ballot(inv);
    if (!inv) {
      atomicAdd(&lh[kd >> 20], 1u);
    } else if ((invb & ((1ull << lane) - 1ull)) == 0ull) {
      atomicAdd(&lh[4095], (uint32_t)__popcll((unsigned long long)invb));
    }
  }
  __syncthreads();
  // sparse flush: populated bins only -> few hundred atomics/block
  for (int b = tid; b < 4096; b += 1024) {
    uint32_t c = lh[b];
    if (c) atomicAdd(&hist1[b], c);
  }
  __threadfence();
  if (tid == 0) amLast = (atomicAdd(&ctrl[4], 1u) == NBLK1 - 1) ? 1u : 0u;
  __syncthreads();
  if (!amLast) return;
  // ---- findcut1 (this block only): scan 16 KB global hist ----
  __threadfence();
  __shared__ uint32_t part[1024];
  int t = tid;
  const uint4* h4 = (const uint4*)hist1;
  uint4 s4 = h4[t];                          // thread t owns bins 4t..4t+3
  uint32_t tot = s4.x + s4.y + s4.z + s4.w;
  part[t] = tot;
  __syncthreads();
  uint32_t inc = tot;
  for (int off = 1; off < 1024; off <<= 1) {
    uint32_t u2 = (t >= off) ? part[t - off] : 0u;
    __syncthreads();
    inc += u2;
    part[t] = inc;
    __syncthreads();
  }
  uint32_t ex = inc - tot;
  if (ex < PRE_K && inc >= PRE_K) {
    uint32_t run = ex;
    uint32_t binv[4] = { s4.x, s4.y, s4.z, s4.w };
    for (int b = 0; b < 4; b++) {
      if (run + binv[b] >= PRE_K) { ctrl[2] = 4 * t + b; ctrl[3] = run; break; }
      run += binv[b];
    }
  }
  if (t == 1023 && inc < PRE_K) { ctrl[2] = 4095u; ctrl[3] = inc; }
}

// ---- K2: refine next 8 bits in coarse bin; last block finds T20 ----
__global__ void __launch_bounds__(1024) k_hist2(const uint32_t* __restrict__ keys,
                                                uint32_t* __restrict__ ctrl,
                                                uint32_t* __restrict__ hist2) {
  __shared__ uint32_t lh[256];
  __shared__ uint32_t amLast;
  int tid = threadIdx.x;
  if (tid < 256) lh[tid] = 0u;
  __syncthreads();
  uint32_t c = ctrl[2];
  for (int i = blockIdx.x * 1024 + tid; i < N_ANCH; i += NBLK1 * 1024) {
    uint32_t k = keys[i];
    if ((k >> 20) == c) atomicAdd(&lh[(k >> 12) & 0xFFu], 1u);
  }
  __syncthreads();
  if (tid < 256) {
    uint32_t v = lh[tid];
    if (v) atomicAdd(&hist2[tid], v);
  }
  __threadfence();
  if (tid == 0) amLast = (atomicAdd(&ctrl[5], 1u) == NBLK1 - 1) ? 1u : 0u;
  __syncthreads();
  if (!amLast) return;
  __threadfence();
  // ---- findcut2: single wave, lane owns 4 sub-bins ----
  if (tid < 64) {
    int lane = tid;
    const uint32_t* p = hist2 + 4 * lane;
    uint32_t b0 = p[0], b1 = p[1], b2 = p[2], b3 = p[3];
    uint32_t tot = b0 + b1 + b2 + b3;
    uint32_t inc = wave_iscan(tot, lane);
    uint32_t base = ctrl[3];
    uint32_t ex = inc - tot;
    if (base + ex < PRE_K && base + inc >= PRE_K) {
      uint32_t run = base + ex;
      uint32_t binv[4] = { b0, b1, b2, b3 };
      for (int b = 0; b < 4; b++) {
        if (run + binv[b] >= PRE_K) { ctrl[1] = (c << 8) | (uint32_t)(4 * lane + b); break; }
        run += binv[b];
      }
    }
    if (lane == 63 && base + inc < PRE_K) ctrl[1] = 0xFFFFFu;  // take everything
  }
}

// ---- K3: compact candidates (key prefix <= T), wave-aggregated atomic ----
__global__ void k_compact(const uint32_t* __restrict__ keys,
                          const uint32_t* __restrict__ ctrl,
                          uint32_t* __restrict__ cnt,
                          uint64_t* __restrict__ cand) {
  int i = blockIdx.x * blockDim.x + threadIdx.x;
  uint32_t T = ctrl[1];
  bool pass = (i < N_ANCH) && ((keys[i] >> 12) <= T);
  uint64_t m = __ballot(pass);
  if (pass) {
    int lane = threadIdx.x & 63;
    int leader = __ffsll((unsigned long long)m) - 1;
    uint32_t base = 0;
    if (lane == leader) base = atomicAdd(cnt, (uint32_t)__popcll((unsigned long long)m));
    base = (uint32_t)__shfl((int)base, leader);
    uint32_t pos = (uint32_t)__popcll((unsigned long long)(m & ((1ull << lane) - 1ull)));
    uint32_t p = base + pos;
    if (p < NS) cand[p] = ((uint64_t)keys[i] << 20) | (uint32_t)i;  // 52-bit packed
  }
}

// ---- K4: re-key (exact sigmoid) + single-block LSD radix sort + gather/decode ----
__global__ void __launch_bounds__(1024) k_sortgather(
    const uint32_t* __restrict__ ctrl,
    const uint64_t* __restrict__ cand,
    const float*  __restrict__ logits,
    const float4* __restrict__ anchors,
    const float4* __restrict__ deltas,
    float4* __restrict__ boxes,
    uint32_t* __restrict__ valid) {
  __shared__ uint64_t buf[NS];            // 56 KiB
  __shared__ uint32_t hist[16 * TILES];   // 7 KiB   hist[d*TILES + t]
  __shared__ uint32_t dtot[16];
  __shared__ uint32_t dbase[16];
  __shared__ uint32_t skipf;
  __shared__ uint32_t mxred[1024];
  int tid = threadIdx.x;
  int wave = tid >> 6, lane = tid & 63;
  uint32_t M = ctrl[0]; if (M > NS) M = NS;
  // re-key: replace logit key with EXACT f32 sigmoid key (reference tie
  // semantics). Track max key so the pad sentinel shares the candidates'
  // common top digits -> top radix passes become uniform and skip.
  uint32_t mymax = 0u;
  for (int i = tid; i < (int)M; i += 1024) {
    uint64_t kk = cand[i];
    uint32_t lk  = (uint32_t)(kk >> 20);
    uint32_t idx = (uint32_t)(kk & 0xFFFFFu);
    uint32_t skey;
    if (lk == 0xFFFFFFFFu) {
      skey = 0xFF800000u;                       // invalid -> -inf key
    } else {
      double xd = (double)logits[idx];
      float s = (float)(1.0 / (1.0 + exp(-xd)));
      skey = 0x7FFFFFFFu & ~__float_as_uint(s); // descending-score -> ascending key
    }
    buf[i] = ((uint64_t)skey << 20) | idx;
    mymax = max(mymax, skey);
  }
  mxred[tid] = mymax;
  __syncthreads();
  for (int off = 512; off > 0; off >>= 1) {
    if (tid < off) mxred[tid] = max(mxred[tid], mxred[tid + off]);
    __syncthreads();
  }
  // pad strictly > any real packed value (idx < 2^20-1 always), sorts last,
  // and shares the max key's digits -> skipf fires on uniform top passes.
  const uint64_t pad = ((uint64_t)mxred[0] << 20) | 0xFFFFFu;
  for (int i = tid; i < NS; i += 1024)
    if (i >= (int)M) buf[i] = pad;
  __syncthreads();
  uint64_t lmask_lt = (1ull << lane) - 1ull;

  for (int p = 0; p < PASSES; p++) {
    int shift = 4 * p;
    for (int i = tid; i < 16 * TILES; i += 1024) hist[i] = 0u;
    uint64_t v[TPW]; int dg[TPW]; int rk[TPW];
    #pragma unroll
    for (int k = 0; k < TPW; k++)
      v[k] = buf[(wave * TPW + k) * 64 + lane];
    __syncthreads();                       // B1: hist zeroed, all elements read
    #pragma unroll
    for (int k = 0; k < TPW; k++) {
      int d = (int)((v[k] >> shift) & 0xF);
      uint64_t m = ~0ull;
      #pragma unroll
      for (int b = 0; b < 4; b++) {
        uint64_t bal = __ballot((d >> b) & 1);
        m &= ((d >> b) & 1) ? bal : ~bal;
      }
      int r = (int)__popcll((unsigned long long)(m & lmask_lt));
      dg[k] = d; rk[k] = r;
      if (r == 0) hist[d * TILES + wave * TPW + k] = (uint32_t)__popcll((unsigned long long)m);
    }
    __syncthreads();                       // B2: hist counts complete
    {                                      // per-digit tile scan: wave w owns digit w
      int d = wave;
      uint32_t c0 = hist[d * TILES + lane];
      uint32_t c1 = (lane < TILES - 64) ? hist[d * TILES + 64 + lane] : 0u;
      uint32_t s0 = wave_iscan(c0, lane);
      uint32_t T0 = (uint32_t)__shfl((int)s0, 63, 64);
      uint32_t s1 = wave_iscan(c1, lane);
      uint32_t T1 = (uint32_t)__shfl((int)s1, 63, 64);
      hist[d * TILES + lane] = s0 - c0;
      if (lane < TILES - 64) hist[d * TILES + 64 + lane] = T0 + (s1 - c1);
      if (lane == 0) dtot[d] = T0 + T1;
    }
    __syncthreads();                       // B3
    if (wave == 0) {
      uint32_t x = (lane < 16) ? dtot[lane] : 0u;
      uint32_t xs = wave_iscan(x, lane);
      if (lane < 16) dbase[lane] = xs - x;
      if (lane == 0) skipf = 0u;
      if (lane < 16 && x == NS) skipf = 1u;   // single-digit pass -> identity scatter
    }
    __syncthreads();                       // B4
    if (!skipf) {
      #pragma unroll
      for (int k = 0; k < TPW; k++) {
        uint32_t dst = dbase[dg[k]] + hist[dg[k] * TILES + wave * TPW + k] + (uint32_t)rk[k];
        buf[dst] = v[k];
      }
    }
    __syncthreads();                       // B5
  }

  // ---- gather + decode epilogue (exact f64-exp decode, 6000 boxes) ----
  for (int r = tid; r < ROWS; r += 1024) {
    if (r >= PRE_K) { boxes[r] = make_float4(0.f, 0.f, 0.f, 0.f); valid[r] = 0u; continue; }
    uint64_t kk = buf[r];
    uint32_t kd = (uint32_t)(kk >> 20);
    if (kk >= pad || kd >= 0xFF800000u) {
      boxes[r] = make_float4(0.f, 0.f, 0.f, 0.f); valid[r] = 0u; continue;
    }
    uint32_t idx = (uint32_t)(kk & 0xFFFFFu);
    float4 a = anchors[idx];
    float4 d = deltas[idx];
    float x1, y1, x2, y2; bool vv;
    decode_box(a.x, a.y, a.z, a.w, d.x, d.y, d.z, d.w, x1, y1, x2, y2, vv);
    boxes[r] = make_float4(x1, y1, x2, y2);
    valid[r] = 1u;
  }
}

// ---- K5: IoU bitmask matrix, row-major mask[row*WORDS + w] ----
__global__ void __launch_bounds__(64) k_iou(const float4* __restrict__ boxes,
                                            uint64_t* __restrict__ mask) {
  int by = blockIdx.y, bx = blockIdx.x;
  if (bx < by) return;               // only words w >= row's group are ever read
  __shared__ float4 cb[64];
  int t = threadIdx.x;
  cb[t] = boxes[bx * 64 + t];
  __syncthreads();
  int i = by * 64 + t;
  float4 b = boxes[i];
  float ax1 = b.x, ay1 = b.y, ax2 = b.z, ay2 = b.w;
  float areaA = __fmul_rn(__fsub_rn(ax2, ax1), __fsub_rn(ay2, ay1));
  uint64_t bits = 0;
  for (int c = 0; c < 64; c++) {
    float4 o = cb[c];
    float areaB = __fmul_rn(__fsub_rn(o.z, o.x), __fsub_rn(o.w, o.y));
    float ix1 = fmaxf(ax1, o.x), iy1 = fmaxf(ay1, o.y);
    float ix2 = fminf(ax2, o.z), iy2 = fminf(ay2, o.w);
    float iw = fmaxf(__fsub_rn(ix2, ix1), 0.0f);
    float ih = fmaxf(__fsub_rn(iy2, iy1), 0.0f);
    float inter = __fmul_rn(iw, ih);
    float uni = __fsub_rn(__fadd_rn(areaA, areaB), inter);
    bool sup = (uni > 0.0f) && (__fdiv_rn(inter, uni) > 0.7f);
    bits |= ((uint64_t)sup) << c;
  }
  mask[(size_t)i * WORDS + bx] = bits;
}

// wave-uniform 64-bit broadcast via v_readlane
__device__ __forceinline__ uint64_t bcast64(uint64_t v, int lane) {
  uint32_t lo = (uint32_t)__builtin_amdgcn_readlane((int)(uint32_t)v, lane);
  uint32_t hi = (uint32_t)__builtin_amdgcn_readlane((int)(uint32_t)(v >> 32), lane);
  return ((uint64_t)hi << 32) | lo;
}

// ---- K6: sequential NMS scan, single wave ----
// Branch-free 64-step decision chain (wave-uniform SALU ops) + unconditional
// whole-group row loads issued before the chain, drained after -> latency
// hidden. __launch_bounds__(64,1): single wave, full VGPR budget.
__global__ void __launch_bounds__(64, 1) k_nms(const uint64_t* __restrict__ mask,
                                               const float4* __restrict__ boxes,
                                               const uint32_t* __restrict__ valid,
                                               float* __restrict__ out) {
  __shared__ uint32_t list[1088];     // cnt(<1000) + up to 64 per group
  int lane = threadIdx.x;
  int wp = (2 * lane < WORDS) ? 2 * lane : 0;  // word pair owned (lanes 47..63 clamped, never read)
  uint64_t rA = 0, rB = 0;            // removed-bit words 2*lane, 2*lane+1
  int cnt = 0;
  uint64_t colv = mask[(size_t)lane * WORDS + 0];     // prefetch group 0 diag
  uint32_t vf = valid[lane];
  for (int g = 0; g < WORDS; g++) {
    int base = g * 64;
    // ---- issue full-group row loads; drained at the fold below ----
    uint64_t vA[64], vB[64];
    #pragma unroll
    for (int r = 0; r < 64; r++) {
      ulonglong2 t2 = *(const ulonglong2*)(mask + (size_t)(base + r) * WORDS + wp);
      vA[r] = t2.x; vB[r] = t2.y;
    }
    uint64_t colv_c = colv;
    uint32_t vf_c = vf;
    if (g + 1 < WORDS) {                              // prefetch group g+1
      colv = mask[(size_t)(base + 64 + lane) * WORDS + (g + 1)];
      vf = valid[base + 64 + lane];
    }
    uint64_t cur = (g & 1) ? bcast64(rB, g >> 1) : bcast64(rA, g >> 1);
    uint64_t vmask = __ballot(vf_c != 0u);
    uint64_t alive = vmask & ~cur;
    // ---- branch-free sequential decision chain: 64 static steps ----
    uint64_t kept = 0;
    #pragma unroll
    for (int r = 0; r < 64; r++) {
      uint64_t mr = bcast64(colv_c, r);               // const-lane readlane, off critical path
      uint64_t take = (alive >> r) & 1ull;
      kept |= take << r;
      alive &= ~(take ? mr : 0ull);                   // diag bit clears r itself
    }
    // ---- record kept rows (parallel, rank by popcount) ----
    uint32_t below = (uint32_t)__popcll((unsigned long long)(kept & ((1ull << lane) - 1ull)));
    if ((kept >> lane) & 1ull) {
      uint32_t pos = (uint32_t)cnt + below;
      if (pos < 1088u) list[pos] = (uint32_t)(base + lane);
    }
    cnt += (int)__popcll((unsigned long long)kept);
    if (cnt >= POST_K) break;                         // later kept rows are dropped anyway
    if (g + 1 >= WORDS) break;
    // ---- fold: select-OR kept rows into removed words (drain happens here) ----
    uint64_t accA = 0, accB = 0;
    #pragma unroll
    for (int r = 0; r < 64; r++) {
      uint64_t s = 0ull - ((kept >> r) & 1ull);
      accA |= vA[r] & s;
      accB |= vB[r] & s;
    }
    rA |= accA;                                       // stale low words never re-read: no guard needed
    rB |= accB;
  }
  __syncthreads();
  float4* outv = (float4*)out;
  for (int k = lane; k < POST_K; k += 64)
    outv[k] = (k < cnt) ? boxes[list[k]] : make_float4(0.f, 0.f, 0.f, 0.f);
}

extern "C" void kernel_launch(void* const* d_in, const int* in_sizes, int n_in,
                              void* d_out, int out_size, void* d_ws, size_t ws_size,
                              hipStream_t stream) {
  const float4* anchors = (const float4*)d_in[1];
  const float4* deltas  = (const float4*)d_in[2];
  const float*  logits  = (const float*)d_in[3];
  char* w = (char*)d_ws;
  uint32_t* keys  = (uint32_t*)(w + OFF_KEYS);
  uint32_t* hist1 = (uint32_t*)(w + OFF_HIST1);
  uint32_t* hist2 = (uint32_t*)(w + OFF_HIST2);
  uint32_t* ctrl  = (uint32_t*)(w + OFF_CTRL);
  uint64_t* cand  = (uint64_t*)(w + OFF_CAND);
  float4*   boxes = (float4*)(w + OFF_BOXES);
  uint32_t* valid = (uint32_t*)(w + OFF_VALID);
  uint64_t* mask  = (uint64_t*)(w + OFF_MASK);
  float*    out   = (float*)d_out;

  hipMemsetAsync(w + OFF_HIST1, 0, 0x4400, stream);  // hist1 (16K) + hist2 (1K)
  hipMemsetAsync(w + OFF_CTRL, 0, 256, stream);      // counters only

  k_decode<<<(N_ANCH + 255) / 256, 256, 0, stream>>>(anchors, deltas, logits, keys);
  k_hist1<<<NBLK1, 1024, 0, stream>>>(keys, hist1, ctrl);
  k_hist2<<<NBLK1, 1024, 0, stream>>>(keys, ctrl, hist2);
  k_compact<<<(N_ANCH + 255) / 256, 256, 0, stream>>>(keys, ctrl, &ctrl[0], cand);
  k_sortgather<<<1, 1024, 0, stream>>>(ctrl, cand, logits, anchors, deltas, boxes, valid);
  k_iou<<<dim3(WORDS, WORDS), 64, 0, stream>>>(boxes, mask);
  k_nms<<<1, 64, 0, stream>>>(mask, boxes, valid, out);
}

// Round 4
// 393.795 us; speedup vs baseline: 1.1265x; 1.1187x over previous
//
#include <hip/hip_runtime.h>
#include <stdint.h>
#include <math.h>

#define N_ANCH   1000000
#define PRE_K    6000
#define POST_K   1000
#define WORDS    94            // ceil(6000/64) -> 6016 bit columns
#define ROWS     6016          // WORDS*64
#define W_IMG    1333.0f
#define H_IMG    800.0f
#define NBLK1    256           // histogram blocks (x1024 threads)

#define NS       7168          // candidate capacity (112 blocks of 64)
#define RBLK     112           // rank blocks

// ws layout (bytes)
#define OFF_KEYS   0x000000u   // u32[1e6] = 4 MiB
#define OFF_HIST1  0x400000u   // u32[4096] global coarse hist (16 KiB)
#define OFF_HIST2  0x404000u   // u32[256]  global refine hist (1 KiB)
#define OFF_CTRL   0x410000u   // [0]=count [1]=T20 [2]=coarse c [3]=base [4],[5]=done ctrs
#define OFF_CAND   0x410100u   // u64[NS] 56 KiB
#define OFF_BOXES  0x41F000u   // float4[6016]
#define OFF_VALID  0x437000u   // u32[6016]
#define OFF_MASK   0x440000u   // u64[6016*94] row-major: mask[row*WORDS + w]

__device__ __forceinline__ float ref_exp(float v) {
  return (float)exp((double)v);   // correctly-rounded f32 exp via double
}

__device__ __forceinline__ void decode_box(float ax, float ay, float az, float aw,
                                           float dx, float dy, float dz, float dw,
                                           float& x1, float& y1, float& x2, float& y2,
                                           bool& valid) {
  // bit-exact replica of reference fp32 op order (no FMA contraction)
  float wa = __fsub_rn(az, ax);
  float ha = __fsub_rn(aw, ay);
  float xa = __fadd_rn(ax, __fmul_rn(0.5f, wa));
  float ya = __fadd_rn(ay, __fmul_rn(0.5f, ha));
  float x  = __fadd_rn(__fmul_rn(dx, wa), xa);
  float y  = __fadd_rn(__fmul_rn(dy, ha), ya);
  float w  = __fmul_rn(ref_exp(dz), wa);
  float h  = __fmul_rn(ref_exp(dw), ha);
  float hw = __fmul_rn(0.5f, w);
  float hh = __fmul_rn(0.5f, h);
  x1 = fminf(fmaxf(__fsub_rn(x, hw), 0.0f), W_IMG - 1.0f);
  y1 = fminf(fmaxf(__fsub_rn(y, hh), 0.0f), H_IMG - 1.0f);
  x2 = fminf(fmaxf(__fadd_rn(x, hw), 0.0f), W_IMG - 1.0f);
  y2 = fminf(fmaxf(__fadd_rn(y, hh), 0.0f), H_IMG - 1.0f);
  valid = (__fsub_rn(x2, x1) >= 16.0f) && (__fsub_rn(y2, y1) >= 16.0f);
}

__device__ __forceinline__ uint32_t wave_iscan(uint32_t x, int lane) {
  #pragma unroll
  for (int off = 1; off < 64; off <<= 1) {
    uint32_t u = __shfl_up(x, off, 64);
    if (lane >= off) x += u;
  }
  return x;
}

// wave-uniform 64-bit broadcast via v_readlane
__device__ __forceinline__ uint64_t bcast64(uint64_t v, int lane) {
  uint32_t lo = (uint32_t)__builtin_amdgcn_readlane((int)(uint32_t)v, lane);
  uint32_t hi = (uint32_t)__builtin_amdgcn_readlane((int)(uint32_t)(v >> 32), lane);
  return ((uint64_t)hi << 32) | lo;
}

// ---- K0: PURE streaming decode -> logit-bit key. No LDS, no atomics, no barriers. ----
__global__ void __launch_bounds__(256) k_decode(const float4* __restrict__ anchors,
                                                const float4* __restrict__ deltas,
                                                const float*  __restrict__ logits,
                                                uint32_t* __restrict__ keys) {
  int i = blockIdx.x * 256 + threadIdx.x;
  if (i >= N_ANCH) return;
  float4 a = anchors[i];
  float4 d = deltas[i];
  // fast f32 decode (filter only; exact op order irrelevant under margin)
  float wa = a.z - a.x, ha = a.w - a.y;
  float xa = a.x + 0.5f * wa, ya = a.y + 0.5f * ha;
  float x = d.x * wa + xa, y = d.y * ha + ya;
  float w = __expf(d.z) * wa, h = __expf(d.w) * ha;
  float fx1 = fminf(fmaxf(x - 0.5f * w, 0.0f), W_IMG - 1.0f);
  float fx2 = fminf(fmaxf(x + 0.5f * w, 0.0f), W_IMG - 1.0f);
  float fy1 = fminf(fmaxf(y - 0.5f * h, 0.0f), H_IMG - 1.0f);
  float fy2 = fminf(fmaxf(y + 0.5f * h, 0.0f), H_IMG - 1.0f);
  float X = fx2 - fx1, Y = fy2 - fy1;
  bool valid = (X >= 16.0f) && (Y >= 16.0f);
  if (fabsf(X - 16.0f) < 0.02f || fabsf(Y - 16.0f) < 0.02f) {
    float ex1, ey1, ex2, ey2; bool vv;      // borderline: exact f64 recheck (rare)
    decode_box(a.x, a.y, a.z, a.w, d.x, d.y, d.z, d.w, ex1, ey1, ex2, ey2, vv);
    valid = vv;
  }
  uint32_t u = __float_as_uint(logits[i]);
  uint32_t o = (u & 0x80000000u) ? ~u : (u | 0x80000000u);  // ascending in logit
  keys[i] = valid ? ~o : 0xFFFFFFFFu;                       // ascending key = descending logit
}

// ---- K1: 12-bit coarse hist over keys (4 MB read); last block finds coarse cut ----
__global__ void __launch_bounds__(1024) k_hist1(const uint32_t* __restrict__ keys,
                                                uint32_t* __restrict__ hist1,
                                                uint32_t* __restrict__ ctrl) {
  __shared__ uint32_t lh[4096];
  __shared__ uint32_t amLast;
  int tid = threadIdx.x;
  int lane = tid & 63;
  for (int b = tid; b < 4096; b += 1024) lh[b] = 0u;
  __syncthreads();
  for (int i = blockIdx.x * 1024 + tid; i < N_ANCH; i += NBLK1 * 1024) {
    uint32_t kd = keys[i];
    bool inv = (kd == 0xFFFFFFFFu);
    uint64_t invb = __ballot(inv);
    if (!inv) {
      atomicAdd(&lh[kd >> 20], 1u);
    } else if ((invb & ((1ull << lane) - 1ull)) == 0ull) {
      atomicAdd(&lh[4095], (uint32_t)__popcll((unsigned long long)invb));
    }
  }
  __syncthreads();
  // sparse flush: populated bins only -> few hundred atomics/block
  for (int b = tid; b < 4096; b += 1024) {
    uint32_t c = lh[b];
    if (c) atomicAdd(&hist1[b], c);
  }
  __threadfence();
  if (tid == 0) amLast = (atomicAdd(&ctrl[4], 1u) == NBLK1 - 1) ? 1u : 0u;
  __syncthreads();
  if (!amLast) return;
  // ---- findcut1 (this block only): scan 16 KB global hist ----
  __threadfence();
  __shared__ uint32_t part[1024];
  int t = tid;
  const uint4* h4 = (const uint4*)hist1;
  uint4 s4 = h4[t];                          // thread t owns bins 4t..4t+3
  uint32_t tot = s4.x + s4.y + s4.z + s4.w;
  part[t] = tot;
  __syncthreads();
  uint32_t inc = tot;
  for (int off = 1; off < 1024; off <<= 1) {
    uint32_t u2 = (t >= off) ? part[t - off] : 0u;
    __syncthreads();
    inc += u2;
    part[t] = inc;
    __syncthreads();
  }
  uint32_t ex = inc - tot;
  if (ex < PRE_K && inc >= PRE_K) {
    uint32_t run = ex;
    uint32_t binv[4] = { s4.x, s4.y, s4.z, s4.w };
    for (int b = 0; b < 4; b++) {
      if (run + binv[b] >= PRE_K) { ctrl[2] = 4 * t + b; ctrl[3] = run; break; }
      run += binv[b];
    }
  }
  if (t == 1023 && inc < PRE_K) { ctrl[2] = 4095u; ctrl[3] = inc; }
}

// ---- K2: refine next 8 bits in coarse bin; last block finds T20 ----
__global__ void __launch_bounds__(1024) k_hist2(const uint32_t* __restrict__ keys,
                                                uint32_t* __restrict__ ctrl,
                                                uint32_t* __restrict__ hist2) {
  __shared__ uint32_t lh[256];
  __shared__ uint32_t amLast;
  int tid = threadIdx.x;
  if (tid < 256) lh[tid] = 0u;
  __syncthreads();
  uint32_t c = ctrl[2];
  for (int i = blockIdx.x * 1024 + tid; i < N_ANCH; i += NBLK1 * 1024) {
    uint32_t k = keys[i];
    if ((k >> 20) == c) atomicAdd(&lh[(k >> 12) & 0xFFu], 1u);
  }
  __syncthreads();
  if (tid < 256) {
    uint32_t v = lh[tid];
    if (v) atomicAdd(&hist2[tid], v);
  }
  __threadfence();
  if (tid == 0) amLast = (atomicAdd(&ctrl[5], 1u) == NBLK1 - 1) ? 1u : 0u;
  __syncthreads();
  if (!amLast) return;
  __threadfence();
  // ---- findcut2: single wave, lane owns 4 sub-bins ----
  if (tid < 64) {
    int lane = tid;
    const uint32_t* p = hist2 + 4 * lane;
    uint32_t b0 = p[0], b1 = p[1], b2 = p[2], b3 = p[3];
    uint32_t tot = b0 + b1 + b2 + b3;
    uint32_t inc = wave_iscan(tot, lane);
    uint32_t base = ctrl[3];
    uint32_t ex = inc - tot;
    if (base + ex < PRE_K && base + inc >= PRE_K) {
      uint32_t run = base + ex;
      uint32_t binv[4] = { b0, b1, b2, b3 };
      for (int b = 0; b < 4; b++) {
        if (run + binv[b] >= PRE_K) { ctrl[1] = (c << 8) | (uint32_t)(4 * lane + b); break; }
        run += binv[b];
      }
    }
    if (lane == 63 && base + inc < PRE_K) ctrl[1] = 0xFFFFFu;  // take everything
  }
}

// ---- K3: compact candidates (logit-key prefix <= T) + exact-sigmoid re-key ----
// Wave-aggregated atomic; order of cand[] is nondeterministic, which is fine:
// k_rank computes positions from VALUES (key64 = skey<<20 | idx, all distinct).
// The f64 sigmoid runs only in the ~7K passing lanes out of 1M -> latency
// hidden by massive TLP.
__global__ void k_compact(const uint32_t* __restrict__ keys,
                          const float* __restrict__ logits,
                          const uint32_t* __restrict__ ctrl,
                          uint32_t* __restrict__ cnt,
                          uint64_t* __restrict__ cand) {
  int i = blockIdx.x * blockDim.x + threadIdx.x;
  uint32_t T = ctrl[1];
  bool pass = (i < N_ANCH) && ((keys[i] >> 12) <= T);
  uint64_t m = __ballot(pass);
  if (pass) {
    uint32_t skey;
    if (keys[i] == 0xFFFFFFFFu) {
      skey = 0xFF800000u;                       // invalid -> -inf key (sorts after all valid)
    } else {
      double xd = (double)logits[i];
      float s = (float)(1.0 / (1.0 + exp(-xd)));
      skey = 0x7FFFFFFFu & ~__float_as_uint(s); // descending-score -> ascending key
    }
    int lane = threadIdx.x & 63;
    int leader = __ffsll((unsigned long long)m) - 1;
    uint32_t base = 0;
    if (lane == leader) base = atomicAdd(cnt, (uint32_t)__popcll((unsigned long long)m));
    base = (uint32_t)__shfl((int)base, leader);
    uint32_t pos = (uint32_t)__popcll((unsigned long long)(m & ((1ull << lane) - 1ull)));
    uint32_t p = base + pos;
    if (p < NS) cand[p] = ((uint64_t)skey << 20) | (uint32_t)i;  // 52-bit packed
  }
}

// ---- K4: rank-by-count + gather/decode (replaces the 13-pass radix sort) ----
// key64 are all DISTINCT (idx embedded) -> rank(i) = #{j: key64_j < key64_i}
// is a bijection onto [0,M) and equals the reference order (score desc, idx
// asc). 112 blocks x 4 waves; lane owns candidate blk*64+lane, each wave
// counts over a quarter of the comparand set via coalesced lane-strided loads
// + 64 unrolled readlane broadcasts (sgpr-pair < vgpr-pair compare).
__global__ void __launch_bounds__(256) k_rank(
    const uint32_t* __restrict__ ctrl,
    const uint64_t* __restrict__ cand,
    const float4* __restrict__ anchors,
    const float4* __restrict__ deltas,
    float4* __restrict__ boxes,
    uint32_t* __restrict__ valid) {
  __shared__ uint32_t part[4][64];
  int tid = threadIdx.x;
  int wv = tid >> 6, lane = tid & 63;
  int i = blockIdx.x * 64 + lane;            // own candidate slot (same for all 4 waves)
  uint32_t M = ctrl[0]; if (M > NS) M = NS;
  uint64_t myk = (i < (int)M) ? cand[i] : ~0ull;
  uint32_t cnt = 0;
  const int QUART = NS / 4;                  // 1792
  int jbase = wv * QUART;
  for (int s = 0; s < QUART / 64; s++) {     // 28 coalesced strips
    int j = jbase + s * 64 + lane;
    uint64_t c = (j < (int)M) ? cand[j] : ~0ull;   // sentinel: contributes 0
    #pragma unroll
    for (int s2 = 0; s2 < 64; s2++) {
      uint64_t kb = bcast64(c, s2);
      cnt += (kb < myk) ? 1u : 0u;
    }
  }
  part[wv][lane] = cnt;
  __syncthreads();
  if (wv != 0) return;
  uint32_t rank = part[0][lane] + part[1][lane] + part[2][lane] + part[3][lane];
  if (i < (int)M && rank < PRE_K) {
    uint32_t skey = (uint32_t)(myk >> 20);
    uint32_t idx  = (uint32_t)(myk & 0xFFFFFu);
    if (skey >= 0xFF800000u) {               // invalid candidate (take-everything case)
      boxes[rank] = make_float4(0.f, 0.f, 0.f, 0.f);
      valid[rank] = 0u;
    } else {
      float4 a = anchors[idx];
      float4 d = deltas[idx];
      float x1, y1, x2, y2; bool vv;
      decode_box(a.x, a.y, a.z, a.w, d.x, d.y, d.z, d.w, x1, y1, x2, y2, vv);
      boxes[rank] = make_float4(x1, y1, x2, y2);
      valid[rank] = 1u;
    }
  }
  // zero-fill all slots never touched by a rank-writer (bijection => no race)
  if ((i >= (int)M || i >= PRE_K) && i < ROWS) {
    boxes[i] = make_float4(0.f, 0.f, 0.f, 0.f);
    valid[i] = 0u;
  }
}

// ---- K5: IoU bitmask matrix, row-major mask[row*WORDS + w] ----
__global__ void __launch_bounds__(64) k_iou(const float4* __restrict__ boxes,
                                            uint64_t* __restrict__ mask) {
  int by = blockIdx.y, bx = blockIdx.x;
  if (bx < by) return;               // only words w >= row's group are ever read
  __shared__ float4 cb[64];
  int t = threadIdx.x;
  cb[t] = boxes[bx * 64 + t];
  __syncthreads();
  int i = by * 64 + t;
  float4 b = boxes[i];
  float ax1 = b.x, ay1 = b.y, ax2 = b.z, ay2 = b.w;
  float areaA = __fmul_rn(__fsub_rn(ax2, ax1), __fsub_rn(ay2, ay1));
  uint64_t bits = 0;
  for (int c = 0; c < 64; c++) {
    float4 o = cb[c];
    float areaB = __fmul_rn(__fsub_rn(o.z, o.x), __fsub_rn(o.w, o.y));
    float ix1 = fmaxf(ax1, o.x), iy1 = fmaxf(ay1, o.y);
    float ix2 = fminf(ax2, o.z), iy2 = fminf(ay2, o.w);
    float iw = fmaxf(__fsub_rn(ix2, ix1), 0.0f);
    float ih = fmaxf(__fsub_rn(iy2, iy1), 0.0f);
    float inter = __fmul_rn(iw, ih);
    float uni = __fsub_rn(__fadd_rn(areaA, areaB), inter);
    bool sup = (uni > 0.0f) && (__fdiv_rn(inter, uni) > 0.7f);
    bits |= ((uint64_t)sup) << c;
  }
  mask[(size_t)i * WORDS + bx] = bits;
}

// ---- K6: sequential NMS scan, single wave ----
// Branch-free 64-step decision chain (wave-uniform SALU ops) + unconditional
// whole-group row loads issued before the chain, drained after -> latency
// hidden. __launch_bounds__(64,1): single wave, full VGPR budget.
__global__ void __launch_bounds__(64, 1) k_nms(const uint64_t* __restrict__ mask,
                                               const float4* __restrict__ boxes,
                                               const uint32_t* __restrict__ valid,
                                               float* __restrict__ out) {
  __shared__ uint32_t list[1088];     // cnt(<1000) + up to 64 per group
  int lane = threadIdx.x;
  int wp = (2 * lane < WORDS) ? 2 * lane : 0;  // word pair owned (lanes 47..63 clamped, never read)
  uint64_t rA = 0, rB = 0;            // removed-bit words 2*lane, 2*lane+1
  int cnt = 0;
  uint64_t colv = mask[(size_t)lane * WORDS + 0];     // prefetch group 0 diag
  uint32_t vf = valid[lane];
  for (int g = 0; g < WORDS; g++) {
    int base = g * 64;
    // ---- issue full-group row loads; drained at the fold below ----
    uint64_t vA[64], vB[64];
    #pragma unroll
    for (int r = 0; r < 64; r++) {
      ulonglong2 t2 = *(const ulonglong2*)(mask + (size_t)(base + r) * WORDS + wp);
      vA[r] = t2.x; vB[r] = t2.y;
    }
    uint64_t colv_c = colv;
    uint32_t vf_c = vf;
    if (g + 1 < WORDS) {                              // prefetch group g+1
      colv = mask[(size_t)(base + 64 + lane) * WORDS + (g + 1)];
      vf = valid[base + 64 + lane];
    }
    uint64_t cur = (g & 1) ? bcast64(rB, g >> 1) : bcast64(rA, g >> 1);
    uint64_t vmask = __ballot(vf_c != 0u);
    uint64_t alive = vmask & ~cur;
    // ---- branch-free sequential decision chain: 64 static steps ----
    uint64_t kept = 0;
    #pragma unroll
    for (int r = 0; r < 64; r++) {
      uint64_t mr = bcast64(colv_c, r);               // const-lane readlane, off critical path
      uint64_t take = (alive >> r) & 1ull;
      kept |= take << r;
      alive &= ~(take ? mr : 0ull);                   // diag bit clears r itself
    }
    // ---- record kept rows (parallel, rank by popcount) ----
    uint32_t below = (uint32_t)__popcll((unsigned long long)(kept & ((1ull << lane) - 1ull)));
    if ((kept >> lane) & 1ull) {
      uint32_t pos = (uint32_t)cnt + below;
      if (pos < 1088u) list[pos] = (uint32_t)(base + lane);
    }
    cnt += (int)__popcll((unsigned long long)kept);
    if (cnt >= POST_K) break;                         // later kept rows are dropped anyway
    if (g + 1 >= WORDS) break;
    // ---- fold: select-OR kept rows into removed words (drain happens here) ----
    uint64_t accA = 0, accB = 0;
    #pragma unroll
    for (int r = 0; r < 64; r++) {
      uint64_t s = 0ull - ((kept >> r) & 1ull);
      accA |= vA[r] & s;
      accB |= vB[r] & s;
    }
    rA |= accA;                                       // stale low words never re-read: no guard needed
    rB |= accB;
  }
  __syncthreads();
  float4* outv = (float4*)out;
  for (int k = lane; k < POST_K; k += 64)
    outv[k] = (k < cnt) ? boxes[list[k]] : make_float4(0.f, 0.f, 0.f, 0.f);
}

extern "C" void kernel_launch(void* const* d_in, const int* in_sizes, int n_in,
                              void* d_out, int out_size, void* d_ws, size_t ws_size,
                              hipStream_t stream) {
  const float4* anchors = (const float4*)d_in[1];
  const float4* deltas  = (const float4*)d_in[2];
  const float*  logits  = (const float*)d_in[3];
  char* w = (char*)d_ws;
  uint32_t* keys  = (uint32_t*)(w + OFF_KEYS);
  uint32_t* hist1 = (uint32_t*)(w + OFF_HIST1);
  uint32_t* hist2 = (uint32_t*)(w + OFF_HIST2);
  uint32_t* ctrl  = (uint32_t*)(w + OFF_CTRL);
  uint64_t* cand  = (uint64_t*)(w + OFF_CAND);
  float4*   boxes = (float4*)(w + OFF_BOXES);
  uint32_t* valid = (uint32_t*)(w + OFF_VALID);
  uint64_t* mask  = (uint64_t*)(w + OFF_MASK);
  float*    out   = (float*)d_out;

  hipMemsetAsync(w + OFF_HIST1, 0, 0x4400, stream);  // hist1 (16K) + hist2 (1K)
  hipMemsetAsync(w + OFF_CTRL, 0, 256, stream);      // counters only

  k_decode<<<(N_ANCH + 255) / 256, 256, 0, stream>>>(anchors, deltas, logits, keys);
  k_hist1<<<NBLK1, 1024, 0, stream>>>(keys, hist1, ctrl);
  k_hist2<<<NBLK1, 1024, 0, stream>>>(keys, ctrl, hist2);
  k_compact<<<(N_ANCH + 255) / 256, 256, 0, stream>>>(keys, logits, ctrl, &ctrl[0], cand);
  k_rank<<<RBLK, 256, 0, stream>>>(ctrl, cand, anchors, deltas, boxes, valid);
  k_iou<<<dim3(WORDS, WORDS), 64, 0, stream>>>(boxes, mask);
  k_nms<<<1, 64, 0, stream>>>(mask, boxes, valid, out);
}

// Round 5
// 279.786 us; speedup vs baseline: 1.5855x; 1.4075x over previous
//
#include <hip/hip_runtime.h>
#include <stdint.h>
#include <math.h>

#define N_ANCH   1000000
#define N4       (N_ANCH / 4)     // 250000 uint4 key packs
#define NBLK4    ((N4 + 1023) / 1024)   // 245 blocks for key scans
#define PRE_K    6000
#define POST_K   1000
#define WORDS    94            // ceil(6000/64) -> 6016 bit columns
#define ROWS     6016          // WORDS*64
#define W_IMG    1333.0f
#define H_IMG    800.0f

#define NS       7168          // candidate capacity (112 blocks of 64)
#define RBLK     112           // rank blocks

// ws layout (bytes)
#define OFF_KEYS   0x000000u   // u32[1e6] = 4 MiB
#define OFF_HIST1  0x400000u   // u32[4096] global coarse hist (16 KiB)
#define OFF_HIST2  0x404000u   // u32[256]  global refine hist (1 KiB)
#define OFF_CTRL   0x410000u   // [0]=count
#define OFF_CAND   0x410100u   // u64[NS] 56 KiB
#define OFF_BOXES  0x41F000u   // float4[6016]
#define OFF_VALID  0x437000u   // u32[6016]
#define OFF_MASK   0x440000u   // u64[6016*94] row-major: mask[row*WORDS + w]

__device__ __forceinline__ float ref_exp(float v) {
  return (float)exp((double)v);   // correctly-rounded f32 exp via double
}

__device__ __forceinline__ void decode_box(float ax, float ay, float az, float aw,
                                           float dx, float dy, float dz, float dw,
                                           float& x1, float& y1, float& x2, float& y2,
                                           bool& valid) {
  // bit-exact replica of reference fp32 op order (no FMA contraction)
  float wa = __fsub_rn(az, ax);
  float ha = __fsub_rn(aw, ay);
  float xa = __fadd_rn(ax, __fmul_rn(0.5f, wa));
  float ya = __fadd_rn(ay, __fmul_rn(0.5f, ha));
  float x  = __fadd_rn(__fmul_rn(dx, wa), xa);
  float y  = __fadd_rn(__fmul_rn(dy, ha), ya);
  float w  = __fmul_rn(ref_exp(dz), wa);
  float h  = __fmul_rn(ref_exp(dw), ha);
  float hw = __fmul_rn(0.5f, w);
  float hh = __fmul_rn(0.5f, h);
  x1 = fminf(fmaxf(__fsub_rn(x, hw), 0.0f), W_IMG - 1.0f);
  y1 = fminf(fmaxf(__fsub_rn(y, hh), 0.0f), H_IMG - 1.0f);
  x2 = fminf(fmaxf(__fadd_rn(x, hw), 0.0f), W_IMG - 1.0f);
  y2 = fminf(fmaxf(__fadd_rn(y, hh), 0.0f), H_IMG - 1.0f);
  valid = (__fsub_rn(x2, x1) >= 16.0f) && (__fsub_rn(y2, y1) >= 16.0f);
}

__device__ __forceinline__ uint32_t wave_iscan(uint32_t x, int lane) {
  #pragma unroll
  for (int off = 1; off < 64; off <<= 1) {
    uint32_t u = __shfl_up(x, off, 64);
    if (lane >= off) x += u;
  }
  return x;
}

// wave-uniform 64-bit broadcast via v_readlane
__device__ __forceinline__ uint64_t bcast64(uint64_t v, int lane) {
  uint32_t lo = (uint32_t)__builtin_amdgcn_readlane((int)(uint32_t)v, lane);
  uint32_t hi = (uint32_t)__builtin_amdgcn_readlane((int)(uint32_t)(v >> 32), lane);
  return ((uint64_t)hi << 32) | lo;
}

// ---- coarse-cut scan, recomputed REDUNDANTLY per block (reads 16 KB L3-cached
// hist; ~1-2 us in parallel across blocks). Requires blockDim.x == 1024.
// Replaces the old threadfence + amLast single-block finalize.
__device__ __forceinline__ void findcut1_dev(const uint32_t* __restrict__ hist1,
                                             uint32_t& c_out, uint32_t& base_out) {
  __shared__ uint32_t part[1024];
  __shared__ uint32_t s_c, s_base;
  int t = threadIdx.x;
  if (t == 0) { s_c = 4095u; s_base = 0u; }
  uint4 s4 = ((const uint4*)hist1)[t];       // thread t owns bins 4t..4t+3
  uint32_t tot = s4.x + s4.y + s4.z + s4.w;
  part[t] = tot;
  __syncthreads();
  uint32_t inc = tot;
  for (int off = 1; off < 1024; off <<= 1) {
    uint32_t u = (t >= off) ? part[t - off] : 0u;
    __syncthreads();
    inc += u;
    part[t] = inc;
    __syncthreads();
  }
  uint32_t ex = inc - tot;
  if (ex < PRE_K && inc >= PRE_K) {
    uint32_t run = ex;
    uint32_t binv[4] = { s4.x, s4.y, s4.z, s4.w };
    for (int b = 0; b < 4; b++) {
      if (run + binv[b] >= PRE_K) { s_c = 4 * t + b; s_base = run; break; }
      run += binv[b];
    }
  }
  if (t == 1023 && inc < PRE_K) { s_c = 4095u; s_base = inc; }  // vestigial fallback
  __syncthreads();
  c_out = s_c; base_out = s_base;
}

// ---- sub-bin cut: 256-entry hist2 -> 20-bit threshold T ----
__device__ __forceinline__ uint32_t findcut2_dev(const uint32_t* __restrict__ hist2,
                                                 uint32_t c, uint32_t base) {
  __shared__ uint32_t s_T;
  int t = threadIdx.x;
  if (t == 0) s_T = 0xFFFFFu;                 // take-everything fallback
  __syncthreads();
  if (t < 64) {
    int lane = t;
    const uint32_t* p = hist2 + 4 * lane;
    uint32_t b0 = p[0], b1 = p[1], b2 = p[2], b3 = p[3];
    uint32_t tot = b0 + b1 + b2 + b3;
    uint32_t inc = wave_iscan(tot, lane);
    uint32_t ex = inc - tot;
    if (base + ex < PRE_K && base + inc >= PRE_K) {
      uint32_t run = base + ex;
      uint32_t binv[4] = { b0, b1, b2, b3 };
      for (int b = 0; b < 4; b++) {
        if (run + binv[b] >= PRE_K) { s_T = (c << 8) | (uint32_t)(4 * lane + b); break; }
        run += binv[b];
      }
    }
  }
  __syncthreads();
  return s_T;
}

// ---- K0: PURE streaming decode -> logit-bit key. No LDS, no atomics, no barriers. ----
__global__ void __launch_bounds__(256) k_decode(const float4* __restrict__ anchors,
                                                const float4* __restrict__ deltas,
                                                const float*  __restrict__ logits,
                                                uint32_t* __restrict__ keys) {
  int i = blockIdx.x * 256 + threadIdx.x;
  if (i >= N_ANCH) return;
  float4 a = anchors[i];
  float4 d = deltas[i];
  // fast f32 decode (filter only; exact op order irrelevant under margin)
  float wa = a.z - a.x, ha = a.w - a.y;
  float xa = a.x + 0.5f * wa, ya = a.y + 0.5f * ha;
  float x = d.x * wa + xa, y = d.y * ha + ya;
  float w = __expf(d.z) * wa, h = __expf(d.w) * ha;
  float fx1 = fminf(fmaxf(x - 0.5f * w, 0.0f), W_IMG - 1.0f);
  float fx2 = fminf(fmaxf(x + 0.5f * w, 0.0f), W_IMG - 1.0f);
  float fy1 = fminf(fmaxf(y - 0.5f * h, 0.0f), H_IMG - 1.0f);
  float fy2 = fminf(fmaxf(y + 0.5f * h, 0.0f), H_IMG - 1.0f);
  float X = fx2 - fx1, Y = fy2 - fy1;
  bool valid = (X >= 16.0f) && (Y >= 16.0f);
  if (fabsf(X - 16.0f) < 0.02f || fabsf(Y - 16.0f) < 0.02f) {
    float ex1, ey1, ex2, ey2; bool vv;      // borderline: exact f64 recheck (rare)
    decode_box(a.x, a.y, a.z, a.w, d.x, d.y, d.z, d.w, ex1, ey1, ex2, ey2, vv);
    valid = vv;
  }
  uint32_t u = __float_as_uint(logits[i]);
  uint32_t o = (u & 0x80000000u) ? ~u : (u | 0x80000000u);  // ascending in logit
  keys[i] = valid ? ~o : 0xFFFFFFFFu;                       // ascending key = descending logit
}

// ---- K1: 12-bit coarse hist over keys (uint4 loads, one pack/thread).
// NO threadfence, NO finalize: kernel boundary publishes hist1.
__global__ void __launch_bounds__(1024) k_histA(const uint4* __restrict__ keys4,
                                                uint32_t* __restrict__ hist1) {
  __shared__ uint32_t lh[4096];
  int tid = threadIdx.x, lane = tid & 63;
  for (int b = tid; b < 4096; b += 1024) lh[b] = 0u;
  __syncthreads();
  int i4 = blockIdx.x * 1024 + tid;
  uint32_t invc = 0;
  if (i4 < N4) {
    uint4 kk = keys4[i4];
    uint32_t ks[4] = { kk.x, kk.y, kk.z, kk.w };
    #pragma unroll
    for (int e = 0; e < 4; e++) {
      if (ks[e] != 0xFFFFFFFFu) atomicAdd(&lh[ks[e] >> 20], 1u);
      else invc++;
    }
  }
  #pragma unroll
  for (int off = 32; off > 0; off >>= 1) invc += __shfl_down(invc, off, 64);
  if (lane == 0 && invc) atomicAdd(&lh[4095], invc);
  __syncthreads();
  for (int b = tid; b < 4096; b += 1024) {     // sparse flush
    uint32_t cv = lh[b];
    if (cv) atomicAdd(&hist1[b], cv);
  }
}

// ---- K2: refine next 8 bits within coarse bin c (c recomputed per block) ----
__global__ void __launch_bounds__(1024) k_hist2(const uint4* __restrict__ keys4,
                                                const uint32_t* __restrict__ hist1,
                                                uint32_t* __restrict__ hist2) {
  uint32_t c, base;
  findcut1_dev(hist1, c, base);
  __shared__ uint32_t lh[256];
  int tid = threadIdx.x;
  if (tid < 256) lh[tid] = 0u;
  __syncthreads();
  int i4 = blockIdx.x * 1024 + tid;
  if (i4 < N4) {
    uint4 kk = keys4[i4];
    uint32_t ks[4] = { kk.x, kk.y, kk.z, kk.w };
    #pragma unroll
    for (int e = 0; e < 4; e++)
      if ((ks[e] >> 20) == c) atomicAdd(&lh[(ks[e] >> 12) & 0xFFu], 1u);
  }
  __syncthreads();
  if (tid < 256) {
    uint32_t v = lh[tid];
    if (v) atomicAdd(&hist2[tid], v);
  }
}

// ---- K3: compact candidates (key prefix <= T, cuts recomputed per block)
// + exact-sigmoid re-key (only ~7K diverged lanes of 1M -> hidden by TLP).
// cand order is nondeterministic; fine, k_rank ranks by VALUE.
__global__ void __launch_bounds__(1024) k_compact(const uint4* __restrict__ keys4,
                                                  const float* __restrict__ logits,
                                                  const uint32_t* __restrict__ hist1,
                                                  const uint32_t* __restrict__ hist2,
                                                  uint32_t* __restrict__ cnt,
                                                  uint64_t* __restrict__ cand) {
  uint32_t c, base;
  findcut1_dev(hist1, c, base);
  uint32_t T = findcut2_dev(hist2, c, base);
  int tid = threadIdx.x, lane = tid & 63;
  int i4 = blockIdx.x * 1024 + tid;
  uint4 kk = make_uint4(~0u, ~0u, ~0u, ~0u);
  if (i4 < N4) kk = keys4[i4];
  uint32_t ks[4] = { kk.x, kk.y, kk.z, kk.w };
  #pragma unroll
  for (int e = 0; e < 4; e++) {
    bool pass = (i4 < N4) && ((ks[e] >> 12) <= T);
    uint64_t m = __ballot(pass);
    if (pass) {
      int i = 4 * i4 + e;
      uint32_t skey;
      if (ks[e] == 0xFFFFFFFFu) {
        skey = 0xFF800000u;                       // invalid -> -inf key
      } else {
        double xd = (double)logits[i];
        float s = (float)(1.0 / (1.0 + exp(-xd)));
        skey = 0x7FFFFFFFu & ~__float_as_uint(s); // descending-score -> ascending key
      }
      int leader = __ffsll((unsigned long long)m) - 1;
      uint32_t bpos = 0;
      if (lane == leader) bpos = atomicAdd(cnt, (uint32_t)__popcll((unsigned long long)m));
      bpos = (uint32_t)__shfl((int)bpos, leader);
      uint32_t pos = (uint32_t)__popcll((unsigned long long)(m & ((1ull << lane) - 1ull)));
      uint32_t p = bpos + pos;
      if (p < NS) cand[p] = ((uint64_t)skey << 20) | (uint32_t)i;  // 52-bit packed
    }
  }
}

// ---- K4: rank-by-count + gather/decode ----
// key64 all DISTINCT (idx embedded) -> rank is a bijection onto [0,M) equal to
// reference order (score desc, idx asc). 112 blocks x 4 waves.
__global__ void __launch_bounds__(256) k_rank(
    const uint32_t* __restrict__ ctrl,
    const uint64_t* __restrict__ cand,
    const float4* __restrict__ anchors,
    const float4* __restrict__ deltas,
    float4* __restrict__ boxes,
    uint32_t* __restrict__ valid) {
  __shared__ uint32_t part[4][64];
  int tid = threadIdx.x;
  int wv = tid >> 6, lane = tid & 63;
  int i = blockIdx.x * 64 + lane;            // own candidate slot (same for all 4 waves)
  uint32_t M = ctrl[0]; if (M > NS) M = NS;
  uint64_t myk = (i < (int)M) ? cand[i] : ~0ull;
  uint32_t cnt = 0;
  const int QUART = NS / 4;                  // 1792
  int jbase = wv * QUART;
  for (int s = 0; s < QUART / 64; s++) {     // 28 coalesced strips
    int j = jbase + s * 64 + lane;
    uint64_t c = (j < (int)M) ? cand[j] : ~0ull;   // sentinel: contributes 0
    #pragma unroll
    for (int s2 = 0; s2 < 64; s2++) {
      uint64_t kb = bcast64(c, s2);
      cnt += (kb < myk) ? 1u : 0u;
    }
  }
  part[wv][lane] = cnt;
  __syncthreads();
  if (wv != 0) return;
  uint32_t rank = part[0][lane] + part[1][lane] + part[2][lane] + part[3][lane];
  if (i < (int)M && rank < PRE_K) {
    uint32_t skey = (uint32_t)(myk >> 20);
    uint32_t idx  = (uint32_t)(myk & 0xFFFFFu);
    if (skey >= 0xFF800000u) {               // invalid candidate (take-everything case)
      boxes[rank] = make_float4(0.f, 0.f, 0.f, 0.f);
      valid[rank] = 0u;
    } else {
      float4 a = anchors[idx];
      float4 d = deltas[idx];
      float x1, y1, x2, y2; bool vv;
      decode_box(a.x, a.y, a.z, a.w, d.x, d.y, d.z, d.w, x1, y1, x2, y2, vv);
      boxes[rank] = make_float4(x1, y1, x2, y2);
      valid[rank] = 1u;
    }
  }
  // zero-fill all slots never touched by a rank-writer (bijection => no race)
  if ((i >= (int)M || i >= PRE_K) && i < ROWS) {
    boxes[i] = make_float4(0.f, 0.f, 0.f, 0.f);
    valid[i] = 0u;
  }
}

// ---- K5: IoU bitmask matrix, row-major mask[row*WORDS + w] ----
__global__ void __launch_bounds__(64) k_iou(const float4* __restrict__ boxes,
                                            uint64_t* __restrict__ mask) {
  int by = blockIdx.y, bx = blockIdx.x;
  if (bx < by) return;               // only words w >= row's group are ever read
  __shared__ float4 cb[64];
  int t = threadIdx.x;
  cb[t] = boxes[bx * 64 + t];
  __syncthreads();
  int i = by * 64 + t;
  float4 b = boxes[i];
  float ax1 = b.x, ay1 = b.y, ax2 = b.z, ay2 = b.w;
  float areaA = __fmul_rn(__fsub_rn(ax2, ax1), __fsub_rn(ay2, ay1));
  uint64_t bits = 0;
  for (int c = 0; c < 64; c++) {
    float4 o = cb[c];
    float areaB = __fmul_rn(__fsub_rn(o.z, o.x), __fsub_rn(o.w, o.y));
    float ix1 = fmaxf(ax1, o.x), iy1 = fmaxf(ay1, o.y);
    float ix2 = fminf(ax2, o.z), iy2 = fminf(ay2, o.w);
    float iw = fmaxf(__fsub_rn(ix2, ix1), 0.0f);
    float ih = fmaxf(__fsub_rn(iy2, iy1), 0.0f);
    float inter = __fmul_rn(iw, ih);
    float uni = __fsub_rn(__fadd_rn(areaA, areaB), inter);
    bool sup = (uni > 0.0f) && (__fdiv_rn(inter, uni) > 0.7f);
    bits |= ((uint64_t)sup) << c;
  }
  mask[(size_t)i * WORDS + bx] = bits;
}

// ---- K6: sequential NMS scan, single wave ----
// Branch-free 64-step decision chain (wave-uniform SALU ops) + unconditional
// whole-group row loads issued before the chain, drained after -> latency
// hidden. __launch_bounds__(64,1): single wave, full VGPR budget.
__global__ void __launch_bounds__(64, 1) k_nms(const uint64_t* __restrict__ mask,
                                               const float4* __restrict__ boxes,
                                               const uint32_t* __restrict__ valid,
                                               float* __restrict__ out) {
  __shared__ uint32_t list[1088];     // cnt(<1000) + up to 64 per group
  int lane = threadIdx.x;
  int wp = (2 * lane < WORDS) ? 2 * lane : 0;  // word pair owned (lanes 47..63 clamped, never read)
  uint64_t rA = 0, rB = 0;            // removed-bit words 2*lane, 2*lane+1
  int cnt = 0;
  uint64_t colv = mask[(size_t)lane * WORDS + 0];     // prefetch group 0 diag
  uint32_t vf = valid[lane];
  for (int g = 0; g < WORDS; g++) {
    int base = g * 64;
    // ---- issue full-group row loads; drained at the fold below ----
    uint64_t vA[64], vB[64];
    #pragma unroll
    for (int r = 0; r < 64; r++) {
      ulonglong2 t2 = *(const ulonglong2*)(mask + (size_t)(base + r) * WORDS + wp);
      vA[r] = t2.x; vB[r] = t2.y;
    }
    uint64_t colv_c = colv;
    uint32_t vf_c = vf;
    if (g + 1 < WORDS) {                              // prefetch group g+1
      colv = mask[(size_t)(base + 64 + lane) * WORDS + (g + 1)];
      vf = valid[base + 64 + lane];
    }
    uint64_t cur = (g & 1) ? bcast64(rB, g >> 1) : bcast64(rA, g >> 1);
    uint64_t vmask = __ballot(vf_c != 0u);
    uint64_t alive = vmask & ~cur;
    // ---- branch-free sequential decision chain: 64 static steps ----
    uint64_t kept = 0;
    #pragma unroll
    for (int r = 0; r < 64; r++) {
      uint64_t mr = bcast64(colv_c, r);               // const-lane readlane, off critical path
      uint64_t take = (alive >> r) & 1ull;
      kept |= take << r;
      alive &= ~(take ? mr : 0ull);                   // diag bit clears r itself
    }
    // ---- record kept rows (parallel, rank by popcount) ----
    uint32_t below = (uint32_t)__popcll((unsigned long long)(kept & ((1ull << lane) - 1ull)));
    if ((kept >> lane) & 1ull) {
      uint32_t pos = (uint32_t)cnt + below;
      if (pos < 1088u) list[pos] = (uint32_t)(base + lane);
    }
    cnt += (int)__popcll((unsigned long long)kept);
    if (cnt >= POST_K) break;                         // later kept rows are dropped anyway
    if (g + 1 >= WORDS) break;
    // ---- fold: select-OR kept rows into removed words (drain happens here) ----
    uint64_t accA = 0, accB = 0;
    #pragma unroll
    for (int r = 0; r < 64; r++) {
      uint64_t s = 0ull - ((kept >> r) & 1ull);
      accA |= vA[r] & s;
      accB |= vB[r] & s;
    }
    rA |= accA;                                       // stale low words never re-read: no guard needed
    rB |= accB;
  }
  __syncthreads();
  float4* outv = (float4*)out;
  for (int k = lane; k < POST_K; k += 64)
    outv[k] = (k < cnt) ? boxes[list[k]] : make_float4(0.f, 0.f, 0.f, 0.f);
}

extern "C" void kernel_launch(void* const* d_in, const int* in_sizes, int n_in,
                              void* d_out, int out_size, void* d_ws, size_t ws_size,
                              hipStream_t stream) {
  const float4* anchors = (const float4*)d_in[1];
  const float4* deltas  = (const float4*)d_in[2];
  const float*  logits  = (const float*)d_in[3];
  char* w = (char*)d_ws;
  uint32_t* keys  = (uint32_t*)(w + OFF_KEYS);
  uint32_t* hist1 = (uint32_t*)(w + OFF_HIST1);
  uint32_t* hist2 = (uint32_t*)(w + OFF_HIST2);
  uint32_t* ctrl  = (uint32_t*)(w + OFF_CTRL);
  uint64_t* cand  = (uint64_t*)(w + OFF_CAND);
  float4*   boxes = (float4*)(w + OFF_BOXES);
  uint32_t* valid = (uint32_t*)(w + OFF_VALID);
  uint64_t* mask  = (uint64_t*)(w + OFF_MASK);
  float*    out   = (float*)d_out;

  hipMemsetAsync(w + OFF_HIST1, 0, 0x4400, stream);  // hist1 (16K) + hist2 (1K)
  hipMemsetAsync(w + OFF_CTRL, 0, 256, stream);      // counters only

  k_decode<<<(N_ANCH + 255) / 256, 256, 0, stream>>>(anchors, deltas, logits, keys);
  k_histA<<<NBLK4, 1024, 0, stream>>>((const uint4*)keys, hist1);
  k_hist2<<<NBLK4, 1024, 0, stream>>>((const uint4*)keys, hist1, hist2);
  k_compact<<<NBLK4, 1024, 0, stream>>>((const uint4*)keys, logits, hist1, hist2, &ctrl[0], cand);
  k_rank<<<RBLK, 256, 0, stream>>>(ctrl, cand, anchors, deltas, boxes, valid);
  k_iou<<<dim3(WORDS, WORDS), 64, 0, stream>>>(boxes, mask);
  k_nms<<<1, 64, 0, stream>>>(mask, boxes, valid, out);
}

// Round 7
// 239.516 us; speedup vs baseline: 1.8521x; 1.1681x over previous
//
#include <hip/hip_runtime.h>
#include <stdint.h>
#include <math.h>

#define N_ANCH   1000000
#define N4       (N_ANCH / 4)          // 250000 uint4 key packs
#define NBLK4    ((N4 + 1023) / 1024)  // 245 blocks (1024-thr kernels)
#define NBLK256  ((N4 + 255) / 256)    // 977 blocks (256-thr kernels)
#define PRE_K    6000
#define POST_K   1000
#define WORDS    94            // ceil(6000/64) -> 6016 bit columns
#define ROWS     6016          // WORDS*64
#define W_IMG    1333.0f
#define H_IMG    800.0f

#define NS       7168          // candidate capacity (112 blocks of 64)
#define RBLK     112           // rank blocks

// ws layout (bytes)
#define OFF_KEYS   0x000000u   // u32[1e6] = 4 MiB
#define OFF_HIST1  0x400000u   // u32[4096] global coarse hist (16 KiB)
#define OFF_HIST2  0x404000u   // u32[256]  global refine hist (1 KiB)
#define OFF_CTRL   0x410000u   // [0]=count [1]=T20 [2]=coarse c [3]=base
#define OFF_CAND   0x410100u   // u64[NS] 56 KiB
#define OFF_BOXES  0x41F000u   // float4[6016]
#define OFF_VALID  0x437000u   // u32[6016]
#define OFF_MASK   0x440000u   // u64[6016*94] row-major: mask[row*WORDS + w]

__device__ __forceinline__ float ref_exp(float v) {
  return (float)exp((double)v);   // correctly-rounded f32 exp via double
}

__device__ __forceinline__ void decode_box(float ax, float ay, float az, float aw,
                                           float dx, float dy, float dz, float dw,
                                           float& x1, float& y1, float& x2, float& y2,
                                           bool& valid) {
  // bit-exact replica of reference fp32 op order (no FMA contraction)
  float wa = __fsub_rn(az, ax);
  float ha = __fsub_rn(aw, ay);
  float xa = __fadd_rn(ax, __fmul_rn(0.5f, wa));
  float ya = __fadd_rn(ay, __fmul_rn(0.5f, ha));
  float x  = __fadd_rn(__fmul_rn(dx, wa), xa);
  float y  = __fadd_rn(__fmul_rn(dy, ha), ya);
  float w  = __fmul_rn(ref_exp(dz), wa);
  float h  = __fmul_rn(ref_exp(dw), ha);
  float hw = __fmul_rn(0.5f, w);
  float hh = __fmul_rn(0.5f, h);
  x1 = fminf(fmaxf(__fsub_rn(x, hw), 0.0f), W_IMG - 1.0f);
  y1 = fminf(fmaxf(__fsub_rn(y, hh), 0.0f), H_IMG - 1.0f);
  x2 = fminf(fmaxf(__fadd_rn(x, hw), 0.0f), W_IMG - 1.0f);
  y2 = fminf(fmaxf(__fadd_rn(y, hh), 0.0f), H_IMG - 1.0f);
  valid = (__fsub_rn(x2, x1) >= 16.0f) && (__fsub_rn(y2, y1) >= 16.0f);
}

__device__ __forceinline__ uint32_t wave_iscan(uint32_t x, int lane) {
  #pragma unroll
  for (int off = 1; off < 64; off <<= 1) {
    uint32_t u = __shfl_up(x, off, 64);
    if (lane >= off) x += u;
  }
  return x;
}

// wave-uniform 64-bit broadcast via v_readlane
__device__ __forceinline__ uint64_t bcast64(uint64_t v, int lane) {
  uint32_t lo = (uint32_t)__builtin_amdgcn_readlane((int)(uint32_t)v, lane);
  uint32_t hi = (uint32_t)__builtin_amdgcn_readlane((int)(uint32_t)(v >> 32), lane);
  return ((uint64_t)hi << 32) | lo;
}

// ---- K0: PURE streaming decode -> logit-bit key. No LDS, no atomics, no barriers. ----
__global__ void __launch_bounds__(256) k_decode(const float4* __restrict__ anchors,
                                                const float4* __restrict__ deltas,
                                                const float*  __restrict__ logits,
                                                uint32_t* __restrict__ keys) {
  int i = blockIdx.x * 256 + threadIdx.x;
  if (i >= N_ANCH) return;
  float4 a = anchors[i];
  float4 d = deltas[i];
  // fast f32 decode (filter only; exact op order irrelevant under margin)
  float wa = a.z - a.x, ha = a.w - a.y;
  float xa = a.x + 0.5f * wa, ya = a.y + 0.5f * ha;
  float x = d.x * wa + xa, y = d.y * ha + ya;
  float w = __expf(d.z) * wa, h = __expf(d.w) * ha;
  float fx1 = fminf(fmaxf(x - 0.5f * w, 0.0f), W_IMG - 1.0f);
  float fx2 = fminf(fmaxf(x + 0.5f * w, 0.0f), W_IMG - 1.0f);
  float fy1 = fminf(fmaxf(y - 0.5f * h, 0.0f), H_IMG - 1.0f);
  float fy2 = fminf(fmaxf(y + 0.5f * h, 0.0f), H_IMG - 1.0f);
  float X = fx2 - fx1, Y = fy2 - fy1;
  bool valid = (X >= 16.0f) && (Y >= 16.0f);
  if (fabsf(X - 16.0f) < 0.02f || fabsf(Y - 16.0f) < 0.02f) {
    float ex1, ey1, ex2, ey2; bool vv;      // borderline: exact f64 recheck (rare)
    decode_box(a.x, a.y, a.z, a.w, d.x, d.y, d.z, d.w, ex1, ey1, ex2, ey2, vv);
    valid = vv;
  }
  uint32_t u = __float_as_uint(logits[i]);
  uint32_t o = (u & 0x80000000u) ? ~u : (u | 0x80000000u);  // ascending in logit
  keys[i] = valid ? ~o : 0xFFFFFFFFu;                       // ascending key = descending logit
}

// ---- K1: 12-bit coarse hist over keys (uint4 loads, one pack/thread). ----
__global__ void __launch_bounds__(1024) k_histA(const uint4* __restrict__ keys4,
                                                uint32_t* __restrict__ hist1) {
  __shared__ uint32_t lh[4096];
  int tid = threadIdx.x, lane = tid & 63;
  for (int b = tid; b < 4096; b += 1024) lh[b] = 0u;
  __syncthreads();
  int i4 = blockIdx.x * 1024 + tid;
  uint32_t invc = 0;
  if (i4 < N4) {
    uint4 kk = keys4[i4];
    uint32_t ks[4] = { kk.x, kk.y, kk.z, kk.w };
    #pragma unroll
    for (int e = 0; e < 4; e++) {
      if (ks[e] != 0xFFFFFFFFu) atomicAdd(&lh[ks[e] >> 20], 1u);
      else invc++;
    }
  }
  #pragma unroll
  for (int off = 32; off > 0; off >>= 1) invc += __shfl_down(invc, off, 64);
  if (lane == 0 && invc) atomicAdd(&lh[4095], invc);
  __syncthreads();
  for (int b = tid; b < 4096; b += 1024) {     // sparse flush
    uint32_t cv = lh[b];
    if (cv) atomicAdd(&hist1[b], cv);
  }
}

// ---- K1b: coarse cut, ONE tiny block. Writes ctrl[2]=c, ctrl[3]=base.
// Kernel boundary publishes ctrl (no fences needed).
__global__ void __launch_bounds__(1024) k_cut1(const uint32_t* __restrict__ hist1,
                                               uint32_t* __restrict__ ctrl) {
  __shared__ uint32_t part[1024];
  int t = threadIdx.x;
  uint4 s4 = ((const uint4*)hist1)[t];       // thread t owns bins 4t..4t+3
  uint32_t tot = s4.x + s4.y + s4.z + s4.w;
  part[t] = tot;
  __syncthreads();
  uint32_t inc = tot;
  for (int off = 1; off < 1024; off <<= 1) {
    uint32_t u = (t >= off) ? part[t - off] : 0u;
    __syncthreads();
    inc += u;
    part[t] = inc;
    __syncthreads();
  }
  uint32_t ex = inc - tot;
  if (ex < PRE_K && inc >= PRE_K) {
    uint32_t run = ex;
    uint32_t binv[4] = { s4.x, s4.y, s4.z, s4.w };
    for (int b = 0; b < 4; b++) {
      if (run + binv[b] >= PRE_K) { ctrl[2] = 4 * t + b; ctrl[3] = run; break; }
      run += binv[b];
    }
  }
  if (t == 1023 && inc < PRE_K) { ctrl[2] = 4095u; ctrl[3] = inc; }  // take everything
}

// ---- K2: refine next 8 bits within coarse bin c (pure streaming, 256 thr) ----
__global__ void __launch_bounds__(256) k_hist2(const uint4* __restrict__ keys4,
                                               const uint32_t* __restrict__ ctrl,
                                               uint32_t* __restrict__ hist2) {
  __shared__ uint32_t lh[256];
  int tid = threadIdx.x;
  lh[tid] = 0u;
  __syncthreads();
  uint32_t c = ctrl[2];
  int i4 = blockIdx.x * 256 + tid;
  if (i4 < N4) {
    uint4 kk = keys4[i4];
    uint32_t ks[4] = { kk.x, kk.y, kk.z, kk.w };
    #pragma unroll
    for (int e = 0; e < 4; e++)
      if ((ks[e] >> 20) == c) atomicAdd(&lh[(ks[e] >> 12) & 0xFFu], 1u);
  }
  __syncthreads();
  uint32_t v = lh[tid];
  if (v) atomicAdd(&hist2[tid], v);    // most blocks: zero atomics
}

// ---- K2b: sub-bin cut, ONE wave. Writes ctrl[1]=T (20-bit threshold). ----
__global__ void __launch_bounds__(64) k_cut2(const uint32_t* __restrict__ hist2,
                                             uint32_t* __restrict__ ctrl) {
  int lane = threadIdx.x;
  uint32_t c = ctrl[2], base = ctrl[3];
  const uint32_t* p = hist2 + 4 * lane;
  uint32_t b0 = p[0], b1 = p[1], b2 = p[2], b3 = p[3];
  uint32_t tot = b0 + b1 + b2 + b3;
  uint32_t inc = wave_iscan(tot, lane);
  uint32_t ex = inc - tot;
  bool found = false;
  if (base + ex < PRE_K && base + inc >= PRE_K) {
    uint32_t run = base + ex;
    uint32_t binv[4] = { b0, b1, b2, b3 };
    for (int b = 0; b < 4; b++) {
      if (run + binv[b] >= PRE_K) { ctrl[1] = (c << 8) | (uint32_t)(4 * lane + b); found = true; break; }
      run += binv[b];
    }
  }
  uint64_t fb = __ballot(found);
  if (lane == 0 && fb == 0ull) ctrl[1] = 0xFFFFFu;   // take everything
}

// ---- K3: compact candidates (key prefix <= T) + exact-sigmoid re-key ----
// Block-aggregated: ONE global atomic per block (977 total, vs ~5000
// same-address wave-leader atomics before). cand order nondeterministic;
// fine, k_rank ranks by VALUE. ctrl passed non-restrict (cnt aliases ctrl[0]).
__global__ void __launch_bounds__(256) k_compact(const uint4* __restrict__ keys4,
                                                 const float* __restrict__ logits,
                                                 uint32_t* ctrl,
                                                 uint64_t* __restrict__ cand) {
  __shared__ uint32_t wcnt[4];
  __shared__ uint32_t bbase_s;
  int tid = threadIdx.x, lane = tid & 63, wv = tid >> 6;
  uint32_t T = ctrl[1];
  int i4 = blockIdx.x * 256 + tid;
  uint4 kk = make_uint4(~0u, ~0u, ~0u, ~0u);
  if (i4 < N4) kk = keys4[i4];
  uint32_t ks[4] = { kk.x, kk.y, kk.z, kk.w };
  bool pass[4]; uint64_t m[4];
  uint32_t tot = 0;
  #pragma unroll
  for (int e = 0; e < 4; e++) {
    pass[e] = (i4 < N4) && ((ks[e] >> 12) <= T);
    m[e] = __ballot(pass[e]);
    tot += (uint32_t)__popcll((unsigned long long)m[e]);
  }
  if (lane == 0) wcnt[wv] = tot;
  __syncthreads();
  if (tid == 0) {
    uint32_t bt = wcnt[0] + wcnt[1] + wcnt[2] + wcnt[3];
    bbase_s = bt ? atomicAdd(&ctrl[0], bt) : 0u;
  }
  __syncthreads();
  uint32_t wb = bbase_s;
  for (int w2 = 0; w2 < wv; w2++) wb += wcnt[w2];      // wave offset in block
  uint64_t lmask = (1ull << lane) - 1ull;
  #pragma unroll
  for (int e = 0; e < 4; e++) {
    if (pass[e]) {
      int i = 4 * i4 + e;
      uint32_t skey;
      if (ks[e] == 0xFFFFFFFFu) {
        skey = 0xFF800000u;                       // invalid -> -inf key
      } else {
        double xd = (double)logits[i];
        float s = (float)(1.0 / (1.0 + exp(-xd)));
        skey = 0x7FFFFFFFu & ~__float_as_uint(s); // descending-score -> ascending key
      }
      uint32_t p = wb + (uint32_t)__popcll((unsigned long long)(m[e] & lmask));
      if (p < NS) cand[p] = ((uint64_t)skey << 20) | (uint32_t)i;  // 52-bit packed
    }
    wb += (uint32_t)__popcll((unsigned long long)m[e]);
  }
}

// ---- K4: rank-by-count + gather/decode ----
// key64 all DISTINCT (idx embedded) -> rank is a bijection onto [0,M) equal to
// reference order (score desc, idx asc). 112 blocks x 4 waves.
__global__ void __launch_bounds__(256) k_rank(
    const uint32_t* __restrict__ ctrl,
    const uint64_t* __restrict__ cand,
    const float4* __restrict__ anchors,
    const float4* __restrict__ deltas,
    float4* __restrict__ boxes,
    uint32_t* __restrict__ valid) {
  __shared__ uint32_t part[4][64];
  int tid = threadIdx.x;
  int wv = tid >> 6, lane = tid & 63;
  int i = blockIdx.x * 64 + lane;            // own candidate slot (same for all 4 waves)
  uint32_t M = ctrl[0]; if (M > NS) M = NS;
  uint64_t myk = (i < (int)M) ? cand[i] : ~0ull;
  uint32_t cnt = 0;
  const int QUART = NS / 4;                  // 1792
  int jbase = wv * QUART;
  for (int s = 0; s < QUART / 64; s++) {     // 28 coalesced strips
    int j = jbase + s * 64 + lane;
    uint64_t c = (j < (int)M) ? cand[j] : ~0ull;   // sentinel: contributes 0
    #pragma unroll
    for (int s2 = 0; s2 < 64; s2++) {
      uint64_t kb = bcast64(c, s2);
      cnt += (kb < myk) ? 1u : 0u;
    }
  }
  part[wv][lane] = cnt;
  __syncthreads();
  if (wv != 0) return;
  uint32_t rank = part[0][lane] + part[1][lane] + part[2][lane] + part[3][lane];
  if (i < (int)M && rank < PRE_K) {
    uint32_t skey = (uint32_t)(myk >> 20);
    uint32_t idx  = (uint32_t)(myk & 0xFFFFFu);
    if (skey >= 0xFF800000u) {               // invalid candidate (take-everything case)
      boxes[rank] = make_float4(0.f, 0.f, 0.f, 0.f);
      valid[rank] = 0u;
    } else {
      float4 a = anchors[idx];
      float4 d = deltas[idx];
      float x1, y1, x2, y2; bool vv;
      decode_box(a.x, a.y, a.z, a.w, d.x, d.y, d.z, d.w, x1, y1, x2, y2, vv);
      boxes[rank] = make_float4(x1, y1, x2, y2);
      valid[rank] = 1u;
    }
  }
  // zero-fill all slots never touched by a rank-writer (bijection => no race)
  if ((i >= (int)M || i >= PRE_K) && i < ROWS) {
    boxes[i] = make_float4(0.f, 0.f, 0.f, 0.f);
    valid[i] = 0u;
  }
}

// ---- K5: IoU bitmask matrix, row-major mask[row*WORDS + w] ----
__global__ void __launch_bounds__(64) k_iou(const float4* __restrict__ boxes,
                                            uint64_t* __restrict__ mask) {
  int by = blockIdx.y, bx = blockIdx.x;
  if (bx < by) return;               // only words w >= row's group are ever read
  __shared__ float4 cb[64];
  int t = threadIdx.x;
  cb[t] = boxes[bx * 64 + t];
  __syncthreads();
  int i = by * 64 + t;
  float4 b = boxes[i];
  float ax1 = b.x, ay1 = b.y, ax2 = b.z, ay2 = b.w;
  float areaA = __fmul_rn(__fsub_rn(ax2, ax1), __fsub_rn(ay2, ay1));
  uint64_t bits = 0;
  for (int c = 0; c < 64; c++) {
    float4 o = cb[c];
    float areaB = __fmul_rn(__fsub_rn(o.z, o.x), __fsub_rn(o.w, o.y));
    float ix1 = fmaxf(ax1, o.x), iy1 = fmaxf(ay1, o.y);
    float ix2 = fminf(ax2, o.z), iy2 = fminf(ay2, o.w);
    float iw = fmaxf(__fsub_rn(ix2, ix1), 0.0f);
    float ih = fmaxf(__fsub_rn(iy2, iy1), 0.0f);
    float inter = __fmul_rn(iw, ih);
    float uni = __fsub_rn(__fadd_rn(areaA, areaB), inter);
    bool sup = (uni > 0.0f) && (__fdiv_rn(inter, uni) > 0.7f);
    bits |= ((uint64_t)sup) << c;
  }
  mask[(size_t)i * WORDS + bx] = bits;
}

// ---- K6: sequential NMS scan, single wave ----
// Branch-free 64-step decision chain (wave-uniform SALU ops) + unconditional
// whole-group row loads issued before the chain, drained after -> latency
// hidden. __launch_bounds__(64,1): single wave, full VGPR budget.
__global__ void __launch_bounds__(64, 1) k_nms(const uint64_t* __restrict__ mask,
                                               const float4* __restrict__ boxes,
                                               const uint32_t* __restrict__ valid,
                                               float* __restrict__ out) {
  __shared__ uint32_t list[1088];     // cnt(<1000) + up to 64 per group
  int lane = threadIdx.x;
  int wp = (2 * lane < WORDS) ? 2 * lane : 0;  // word pair owned (lanes 47..63 clamped, never read)
  uint64_t rA = 0, rB = 0;            // removed-bit words 2*lane, 2*lane+1
  int cnt = 0;
  uint64_t colv = mask[(size_t)lane * WORDS + 0];     // prefetch group 0 diag
  uint32_t vf = valid[lane];
  for (int g = 0; g < WORDS; g++) {
    int base = g * 64;
    // ---- issue full-group row loads; drained at the fold below ----
    uint64_t vA[64], vB[64];
    #pragma unroll
    for (int r = 0; r < 64; r++) {
      ulonglong2 t2 = *(const ulonglong2*)(mask + (size_t)(base + r) * WORDS + wp);
      vA[r] = t2.x; vB[r] = t2.y;
    }
    uint64_t colv_c = colv;
    uint32_t vf_c = vf;
    if (g + 1 < WORDS) {                              // prefetch group g+1
      colv = mask[(size_t)(base + 64 + lane) * WORDS + (g + 1)];
      vf = valid[base + 64 + lane];
    }
    uint64_t cur = (g & 1) ? bcast64(rB, g >> 1) : bcast64(rA, g >> 1);
    uint64_t vmask = __ballot(vf_c != 0u);
    uint64_t alive = vmask & ~cur;
    // ---- branch-free sequential decision chain: 64 static steps ----
    uint64_t kept = 0;
    #pragma unroll
    for (int r = 0; r < 64; r++) {
      uint64_t mr = bcast64(colv_c, r);               // const-lane readlane, off critical path
      uint64_t take = (alive >> r) & 1ull;
      kept |= take << r;
      alive &= ~(take ? mr : 0ull);                   // diag bit clears r itself
    }
    // ---- record kept rows (parallel, rank by popcount) ----
    uint32_t below = (uint32_t)__popcll((unsigned long long)(kept & ((1ull << lane) - 1ull)));
    if ((kept >> lane) & 1ull) {
      uint32_t pos = (uint32_t)cnt + below;
      if (pos < 1088u) list[pos] = (uint32_t)(base + lane);
    }
    cnt += (int)__popcll((unsigned long long)kept);
    if (cnt >= POST_K) break;                         // later kept rows are dropped anyway
    if (g + 1 >= WORDS) break;
    // ---- fold: select-OR kept rows into removed words (drain happens here) ----
    uint64_t accA = 0, accB = 0;
    #pragma unroll
    for (int r = 0; r < 64; r++) {
      uint64_t s = 0ull - ((kept >> r) & 1ull);
      accA |= vA[r] & s;
      accB |= vB[r] & s;
    }
    rA |= accA;                                       // stale low words never re-read: no guard needed
    rB |= accB;
  }
  __syncthreads();
  float4* outv = (float4*)out;
  for (int k = lane; k < POST_K; k += 64)
    outv[k] = (k < cnt) ? boxes[list[k]] : make_float4(0.f, 0.f, 0.f, 0.f);
}

extern "C" void kernel_launch(void* const* d_in, const int* in_sizes, int n_in,
                              void* d_out, int out_size, void* d_ws, size_t ws_size,
                              hipStream_t stream) {
  const float4* anchors = (const float4*)d_in[1];
  const float4* deltas  = (const float4*)d_in[2];
  const float*  logits  = (const float*)d_in[3];
  char* w = (char*)d_ws;
  uint32_t* keys  = (uint32_t*)(w + OFF_KEYS);
  uint32_t* hist1 = (uint32_t*)(w + OFF_HIST1);
  uint32_t* hist2 = (uint32_t*)(w + OFF_HIST2);
  uint32_t* ctrl  = (uint32_t*)(w + OFF_CTRL);
  uint64_t* cand  = (uint64_t*)(w + OFF_CAND);
  float4*   boxes = (float4*)(w + OFF_BOXES);
  uint32_t* valid = (uint32_t*)(w + OFF_VALID);
  uint64_t* mask  = (uint64_t*)(w + OFF_MASK);
  float*    out   = (float*)d_out;

  hipMemsetAsync(w + OFF_HIST1, 0, 0x4400, stream);  // hist1 (16K) + hist2 (1K)
  hipMemsetAsync(w + OFF_CTRL, 0, 256, stream);      // counters only

  k_decode<<<(N_ANCH + 255) / 256, 256, 0, stream>>>(anchors, deltas, logits, keys);
  k_histA<<<NBLK4, 1024, 0, stream>>>((const uint4*)keys, hist1);
  k_cut1<<<1, 1024, 0, stream>>>(hist1, ctrl);
  k_hist2<<<NBLK256, 256, 0, stream>>>((const uint4*)keys, ctrl, hist2);
  k_cut2<<<1, 64, 0, stream>>>(hist2, ctrl);
  k_compact<<<NBLK256, 256, 0, stream>>>((const uint4*)keys, logits, ctrl, cand);
  k_rank<<<RBLK, 256, 0, stream>>>(ctrl, cand, anchors, deltas, boxes, valid);
  k_iou<<<dim3(WORDS, WORDS), 64, 0, stream>>>(boxes, mask);
  k_nms<<<1, 64, 0, stream>>>(mask, boxes, valid, out);
}

// Round 8
// 227.485 us; speedup vs baseline: 1.9500x; 1.0529x over previous
//
#include <hip/hip_runtime.h>
#include <stdint.h>
#include <math.h>

#define N_ANCH   1000000
#define N4       (N_ANCH / 4)          // 250000 uint4 key packs
#define NBLK4    ((N4 + 1023) / 1024)  // 245 blocks (1024-thr kernels)
#define NBLK256  ((N4 + 255) / 256)    // 977 blocks (256-thr kernels)
#define PRE_K    6000
#define POST_K   1000
#define WORDS    94            // ceil(6000/64) -> 6016 bit columns
#define ROWS     6016          // WORDS*64
#define W_IMG    1333.0f
#define H_IMG    800.0f

#define NS       7168          // candidate capacity (112 blocks of 64)
#define RBLK     112           // rank blocks

#define NMS_WAVES 4
#define RPW       16           // rows per wave in the k_nms fold (64/NMS_WAVES)

// ws layout (bytes)
#define OFF_KEYS   0x000000u   // u32[1e6] = 4 MiB
#define OFF_HIST1  0x400000u   // u32[4096] global coarse hist (16 KiB)
#define OFF_HIST2  0x404000u   // u32[256]  global refine hist (1 KiB)
#define OFF_CTRL   0x410000u   // [0]=count [1]=T20 [2]=coarse c [3]=base
#define OFF_CAND   0x410100u   // u64[NS] 56 KiB
#define OFF_BOXES  0x41F000u   // float4[6016]
#define OFF_VALID  0x437000u   // u32[6016]
#define OFF_MASK   0x440000u   // u64[6016*94] row-major: mask[row*WORDS + w]

__device__ __forceinline__ float ref_exp(float v) {
  return (float)exp((double)v);   // correctly-rounded f32 exp via double
}

__device__ __forceinline__ void decode_box(float ax, float ay, float az, float aw,
                                           float dx, float dy, float dz, float dw,
                                           float& x1, float& y1, float& x2, float& y2,
                                           bool& valid) {
  // bit-exact replica of reference fp32 op order (no FMA contraction)
  float wa = __fsub_rn(az, ax);
  float ha = __fsub_rn(aw, ay);
  float xa = __fadd_rn(ax, __fmul_rn(0.5f, wa));
  float ya = __fadd_rn(ay, __fmul_rn(0.5f, ha));
  float x  = __fadd_rn(__fmul_rn(dx, wa), xa);
  float y  = __fadd_rn(__fmul_rn(dy, ha), ya);
  float w  = __fmul_rn(ref_exp(dz), wa);
  float h  = __fmul_rn(ref_exp(dw), ha);
  float hw = __fmul_rn(0.5f, w);
  float hh = __fmul_rn(0.5f, h);
  x1 = fminf(fmaxf(__fsub_rn(x, hw), 0.0f), W_IMG - 1.0f);
  y1 = fminf(fmaxf(__fsub_rn(y, hh), 0.0f), H_IMG - 1.0f);
  x2 = fminf(fmaxf(__fadd_rn(x, hw), 0.0f), W_IMG - 1.0f);
  y2 = fminf(fmaxf(__fadd_rn(y, hh), 0.0f), H_IMG - 1.0f);
  valid = (__fsub_rn(x2, x1) >= 16.0f) && (__fsub_rn(y2, y1) >= 16.0f);
}

__device__ __forceinline__ uint32_t wave_iscan(uint32_t x, int lane) {
  #pragma unroll
  for (int off = 1; off < 64; off <<= 1) {
    uint32_t u = __shfl_up(x, off, 64);
    if (lane >= off) x += u;
  }
  return x;
}

// wave-uniform 64-bit broadcast via v_readlane
__device__ __forceinline__ uint64_t bcast64(uint64_t v, int lane) {
  uint32_t lo = (uint32_t)__builtin_amdgcn_readlane((int)(uint32_t)v, lane);
  uint32_t hi = (uint32_t)__builtin_amdgcn_readlane((int)(uint32_t)(v >> 32), lane);
  return ((uint64_t)hi << 32) | lo;
}

// ---- K0: PURE streaming decode -> logit-bit key. No LDS, no atomics, no barriers. ----
__global__ void __launch_bounds__(256) k_decode(const float4* __restrict__ anchors,
                                                const float4* __restrict__ deltas,
                                                const float*  __restrict__ logits,
                                                uint32_t* __restrict__ keys) {
  int i = blockIdx.x * 256 + threadIdx.x;
  if (i >= N_ANCH) return;
  float4 a = anchors[i];
  float4 d = deltas[i];
  // fast f32 decode (filter only; exact op order irrelevant under margin)
  float wa = a.z - a.x, ha = a.w - a.y;
  float xa = a.x + 0.5f * wa, ya = a.y + 0.5f * ha;
  float x = d.x * wa + xa, y = d.y * ha + ya;
  float w = __expf(d.z) * wa, h = __expf(d.w) * ha;
  float fx1 = fminf(fmaxf(x - 0.5f * w, 0.0f), W_IMG - 1.0f);
  float fx2 = fminf(fmaxf(x + 0.5f * w, 0.0f), W_IMG - 1.0f);
  float fy1 = fminf(fmaxf(y - 0.5f * h, 0.0f), H_IMG - 1.0f);
  float fy2 = fminf(fmaxf(y + 0.5f * h, 0.0f), H_IMG - 1.0f);
  float X = fx2 - fx1, Y = fy2 - fy1;
  bool valid = (X >= 16.0f) && (Y >= 16.0f);
  if (fabsf(X - 16.0f) < 0.02f || fabsf(Y - 16.0f) < 0.02f) {
    float ex1, ey1, ex2, ey2; bool vv;      // borderline: exact f64 recheck (rare)
    decode_box(a.x, a.y, a.z, a.w, d.x, d.y, d.z, d.w, ex1, ey1, ex2, ey2, vv);
    valid = vv;
  }
  uint32_t u = __float_as_uint(logits[i]);
  uint32_t o = (u & 0x80000000u) ? ~u : (u | 0x80000000u);  // ascending in logit
  keys[i] = valid ? ~o : 0xFFFFFFFFu;                       // ascending key = descending logit
}

// ---- K1: 12-bit coarse hist over keys (uint4 loads, one pack/thread). ----
__global__ void __launch_bounds__(1024) k_histA(const uint4* __restrict__ keys4,
                                                uint32_t* __restrict__ hist1) {
  __shared__ uint32_t lh[4096];
  int tid = threadIdx.x, lane = tid & 63;
  for (int b = tid; b < 4096; b += 1024) lh[b] = 0u;
  __syncthreads();
  int i4 = blockIdx.x * 1024 + tid;
  uint32_t invc = 0;
  if (i4 < N4) {
    uint4 kk = keys4[i4];
    uint32_t ks[4] = { kk.x, kk.y, kk.z, kk.w };
    #pragma unroll
    for (int e = 0; e < 4; e++) {
      if (ks[e] != 0xFFFFFFFFu) atomicAdd(&lh[ks[e] >> 20], 1u);
      else invc++;
    }
  }
  #pragma unroll
  for (int off = 32; off > 0; off >>= 1) invc += __shfl_down(invc, off, 64);
  if (lane == 0 && invc) atomicAdd(&lh[4095], invc);
  __syncthreads();
  for (int b = tid; b < 4096; b += 1024) {     // sparse flush
    uint32_t cv = lh[b];
    if (cv) atomicAdd(&hist1[b], cv);
  }
}

// ---- K1b: coarse cut, ONE tiny block. Writes ctrl[2]=c, ctrl[3]=base.
// Kernel boundary publishes ctrl (no fences needed).
__global__ void __launch_bounds__(1024) k_cut1(const uint32_t* __restrict__ hist1,
                                               uint32_t* __restrict__ ctrl) {
  __shared__ uint32_t part[1024];
  int t = threadIdx.x;
  uint4 s4 = ((const uint4*)hist1)[t];       // thread t owns bins 4t..4t+3
  uint32_t tot = s4.x + s4.y + s4.z + s4.w;
  part[t] = tot;
  __syncthreads();
  uint32_t inc = tot;
  for (int off = 1; off < 1024; off <<= 1) {
    uint32_t u = (t >= off) ? part[t - off] : 0u;
    __syncthreads();
    inc += u;
    part[t] = inc;
    __syncthreads();
  }
  uint32_t ex = inc - tot;
  if (ex < PRE_K && inc >= PRE_K) {
    uint32_t run = ex;
    uint32_t binv[4] = { s4.x, s4.y, s4.z, s4.w };
    for (int b = 0; b < 4; b++) {
      if (run + binv[b] >= PRE_K) { ctrl[2] = 4 * t + b; ctrl[3] = run; break; }
      run += binv[b];
    }
  }
  if (t == 1023 && inc < PRE_K) { ctrl[2] = 4095u; ctrl[3] = inc; }  // take everything
}

// ---- K2: refine next 8 bits within coarse bin c (pure streaming, 256 thr) ----
__global__ void __launch_bounds__(256) k_hist2(const uint4* __restrict__ keys4,
                                               const uint32_t* __restrict__ ctrl,
                                               uint32_t* __restrict__ hist2) {
  __shared__ uint32_t lh[256];
  int tid = threadIdx.x;
  lh[tid] = 0u;
  __syncthreads();
  uint32_t c = ctrl[2];
  int i4 = blockIdx.x * 256 + tid;
  if (i4 < N4) {
    uint4 kk = keys4[i4];
    uint32_t ks[4] = { kk.x, kk.y, kk.z, kk.w };
    #pragma unroll
    for (int e = 0; e < 4; e++)
      if ((ks[e] >> 20) == c) atomicAdd(&lh[(ks[e] >> 12) & 0xFFu], 1u);
  }
  __syncthreads();
  uint32_t v = lh[tid];
  if (v) atomicAdd(&hist2[tid], v);    // most blocks: zero atomics
}

// ---- K2b: sub-bin cut, ONE wave. Writes ctrl[1]=T (20-bit threshold). ----
__global__ void __launch_bounds__(64) k_cut2(const uint32_t* __restrict__ hist2,
                                             uint32_t* __restrict__ ctrl) {
  int lane = threadIdx.x;
  uint32_t c = ctrl[2], base = ctrl[3];
  const uint32_t* p = hist2 + 4 * lane;
  uint32_t b0 = p[0], b1 = p[1], b2 = p[2], b3 = p[3];
  uint32_t tot = b0 + b1 + b2 + b3;
  uint32_t inc = wave_iscan(tot, lane);
  uint32_t ex = inc - tot;
  bool found = false;
  if (base + ex < PRE_K && base + inc >= PRE_K) {
    uint32_t run = base + ex;
    uint32_t binv[4] = { b0, b1, b2, b3 };
    for (int b = 0; b < 4; b++) {
      if (run + binv[b] >= PRE_K) { ctrl[1] = (c << 8) | (uint32_t)(4 * lane + b); found = true; break; }
      run += binv[b];
    }
  }
  uint64_t fb = __ballot(found);
  if (lane == 0 && fb == 0ull) ctrl[1] = 0xFFFFFu;   // take everything
}

// ---- K3: compact candidates (key prefix <= T) + exact-sigmoid re-key ----
// Block-aggregated: ONE global atomic per block. cand order nondeterministic;
// fine, k_rank ranks by VALUE. ctrl passed non-restrict (cnt aliases ctrl[0]).
__global__ void __launch_bounds__(256) k_compact(const uint4* __restrict__ keys4,
                                                 const float* __restrict__ logits,
                                                 uint32_t* ctrl,
                                                 uint64_t* __restrict__ cand) {
  __shared__ uint32_t wcnt[4];
  __shared__ uint32_t bbase_s;
  int tid = threadIdx.x, lane = tid & 63, wv = tid >> 6;
  uint32_t T = ctrl[1];
  int i4 = blockIdx.x * 256 + tid;
  uint4 kk = make_uint4(~0u, ~0u, ~0u, ~0u);
  if (i4 < N4) kk = keys4[i4];
  uint32_t ks[4] = { kk.x, kk.y, kk.z, kk.w };
  bool pass[4]; uint64_t m[4];
  uint32_t tot = 0;
  #pragma unroll
  for (int e = 0; e < 4; e++) {
    pass[e] = (i4 < N4) && ((ks[e] >> 12) <= T);
    m[e] = __ballot(pass[e]);
    tot += (uint32_t)__popcll((unsigned long long)m[e]);
  }
  if (lane == 0) wcnt[wv] = tot;
  __syncthreads();
  if (tid == 0) {
    uint32_t bt = wcnt[0] + wcnt[1] + wcnt[2] + wcnt[3];
    bbase_s = bt ? atomicAdd(&ctrl[0], bt) : 0u;
  }
  __syncthreads();
  uint32_t wb = bbase_s;
  for (int w2 = 0; w2 < wv; w2++) wb += wcnt[w2];      // wave offset in block
  uint64_t lmask = (1ull << lane) - 1ull;
  #pragma unroll
  for (int e = 0; e < 4; e++) {
    if (pass[e]) {
      int i = 4 * i4 + e;
      uint32_t skey;
      if (ks[e] == 0xFFFFFFFFu) {
        skey = 0xFF800000u;                       // invalid -> -inf key
      } else {
        double xd = (double)logits[i];
        float s = (float)(1.0 / (1.0 + exp(-xd)));
        skey = 0x7FFFFFFFu & ~__float_as_uint(s); // descending-score -> ascending key
      }
      uint32_t p = wb + (uint32_t)__popcll((unsigned long long)(m[e] & lmask));
      if (p < NS) cand[p] = ((uint64_t)skey << 20) | (uint32_t)i;  // 52-bit packed
    }
    wb += (uint32_t)__popcll((unsigned long long)m[e]);
  }
}

// ---- K4: rank-by-count + gather/decode ----
// key64 all DISTINCT (idx embedded) -> rank is a bijection onto [0,M) equal to
// reference order (score desc, idx asc). 112 blocks x 4 waves.
__global__ void __launch_bounds__(256) k_rank(
    const uint32_t* __restrict__ ctrl,
    const uint64_t* __restrict__ cand,
    const float4* __restrict__ anchors,
    const float4* __restrict__ deltas,
    float4* __restrict__ boxes,
    uint32_t* __restrict__ valid) {
  __shared__ uint32_t part[4][64];
  int tid = threadIdx.x;
  int wv = tid >> 6, lane = tid & 63;
  int i = blockIdx.x * 64 + lane;            // own candidate slot (same for all 4 waves)
  uint32_t M = ctrl[0]; if (M > NS) M = NS;
  uint64_t myk = (i < (int)M) ? cand[i] : ~0ull;
  uint32_t cnt = 0;
  const int QUART = NS / 4;                  // 1792
  int jbase = wv * QUART;
  for (int s = 0; s < QUART / 64; s++) {     // 28 coalesced strips
    int j = jbase + s * 64 + lane;
    uint64_t c = (j < (int)M) ? cand[j] : ~0ull;   // sentinel: contributes 0
    #pragma unroll
    for (int s2 = 0; s2 < 64; s2++) {
      uint64_t kb = bcast64(c, s2);
      cnt += (kb < myk) ? 1u : 0u;
    }
  }
  part[wv][lane] = cnt;
  __syncthreads();
  if (wv != 0) return;
  uint32_t rank = part[0][lane] + part[1][lane] + part[2][lane] + part[3][lane];
  if (i < (int)M && rank < PRE_K) {
    uint32_t skey = (uint32_t)(myk >> 20);
    uint32_t idx  = (uint32_t)(myk & 0xFFFFFu);
    if (skey >= 0xFF800000u) {               // invalid candidate (take-everything case)
      boxes[rank] = make_float4(0.f, 0.f, 0.f, 0.f);
      valid[rank] = 0u;
    } else {
      float4 a = anchors[idx];
      float4 d = deltas[idx];
      float x1, y1, x2, y2; bool vv;
      decode_box(a.x, a.y, a.z, a.w, d.x, d.y, d.z, d.w, x1, y1, x2, y2, vv);
      boxes[rank] = make_float4(x1, y1, x2, y2);
      valid[rank] = 1u;
    }
  }
  // zero-fill all slots never touched by a rank-writer (bijection => no race)
  if ((i >= (int)M || i >= PRE_K) && i < ROWS) {
    boxes[i] = make_float4(0.f, 0.f, 0.f, 0.f);
    valid[i] = 0u;
  }
}

// ---- K5: IoU bitmask matrix, row-major mask[row*WORDS + w] ----
__global__ void __launch_bounds__(64) k_iou(const float4* __restrict__ boxes,
                                            uint64_t* __restrict__ mask) {
  int by = blockIdx.y, bx = blockIdx.x;
  if (bx < by) return;               // only words w >= row's group are ever read
  __shared__ float4 cb[64];
  int t = threadIdx.x;
  cb[t] = boxes[bx * 64 + t];
  __syncthreads();
  int i = by * 64 + t;
  float4 b = boxes[i];
  float ax1 = b.x, ay1 = b.y, ax2 = b.z, ay2 = b.w;
  float areaA = __fmul_rn(__fsub_rn(ax2, ax1), __fsub_rn(ay2, ay1));
  uint64_t bits = 0;
  for (int c = 0; c < 64; c++) {
    float4 o = cb[c];
    float areaB = __fmul_rn(__fsub_rn(o.z, o.x), __fsub_rn(o.w, o.y));
    float ix1 = fmaxf(ax1, o.x), iy1 = fmaxf(ay1, o.y);
    float ix2 = fminf(ax2, o.z), iy2 = fminf(ay2, o.w);
    float iw = fmaxf(__fsub_rn(ix2, ix1), 0.0f);
    float ih = fmaxf(__fsub_rn(iy2, iy1), 0.0f);
    float inter = __fmul_rn(iw, ih);
    float uni = __fsub_rn(__fadd_rn(areaA, areaB), inter);
    bool sup = (uni > 0.0f) && (__fdiv_rn(inter, uni) > 0.7f);
    bits |= ((uint64_t)sup) << c;
  }
  mask[(size_t)i * WORDS + bx] = bits;
}

// ---- K6: sequential NMS scan — 4-wave cooperative ----
// v3: round-7 counters showed VGPR_Count=144 < the 256 needed for the old
// single-wave vA/vB[64] batch -> compiler spilled the fold batch to scratch
// (48 KB/group round-trip). Fix: the wave-uniform SALU decision chain is
// REPLICATED in 4 waves (4 SIMDs, no extra wall time, no communication);
// the fold is SPLIT by rows (wave w folds rows 16w..16w+15, vA/vB[16] = 64
// VGPR, no spill) into per-wave partial removed words. Only the single word
// removed[g+1] crosses waves per group, via a double-buffered 8-word LDS
// slot -> ONE barrier per group.
__global__ void __launch_bounds__(256, 1) k_nms(const uint64_t* __restrict__ mask,
                                                const float4* __restrict__ boxes,
                                                const uint32_t* __restrict__ valid,
                                                float* __restrict__ out) {
  __shared__ uint32_t list[1088];          // kept rows in scan order
  __shared__ uint64_t remS[2][NMS_WAVES];  // double-buffered cross-wave word exchange
  int tid = threadIdx.x;
  int lane = tid & 63, wv = tid >> 6;
  int wp = (2 * lane < WORDS) ? 2 * lane : 0;  // word pair owned (lanes 47..63 clamped, never read)
  uint64_t rA = 0, rB = 0;                 // THIS WAVE's partial removed words 2*lane, 2*lane+1
  int cnt = 0;
  if (tid < 2 * NMS_WAVES) ((uint64_t*)remS)[tid] = 0ull;
  uint64_t colv = mask[(size_t)lane * WORDS + 0];     // group-0 diag (all waves redundant)
  uint32_t vf = valid[lane];
  __syncthreads();
  for (int g = 0; g < WORDS; g++) {
    int base = g * 64;
    // ---- issue this wave's 16-row loads; drained at the fold below ----
    uint64_t vA[RPW], vB[RPW];
    #pragma unroll
    for (int k = 0; k < RPW; k++) {
      ulonglong2 t2 = *(const ulonglong2*)(mask + (size_t)(base + wv * RPW + k) * WORDS + wp);
      vA[k] = t2.x; vB[k] = t2.y;
    }
    uint64_t colv_c = colv;
    uint32_t vf_c = vf;
    if (g + 1 < WORDS) {                              // prefetch next diag + valid
      colv = mask[(size_t)(base + 64 + lane) * WORDS + (g + 1)];
      vf = valid[base + 64 + lane];
    }
    // cur = OR of the 4 waves' partial removed word g (published last iter)
    uint64_t cur = remS[g & 1][0] | remS[g & 1][1] | remS[g & 1][2] | remS[g & 1][3];
    uint64_t vmask = __ballot(vf_c != 0u);
    uint64_t alive = vmask & ~cur;
    // ---- branch-free decision chain: replicated in all 4 waves ----
    uint64_t kept = 0;
    #pragma unroll
    for (int r = 0; r < 64; r++) {
      uint64_t mr = bcast64(colv_c, r);
      uint64_t take = (alive >> r) & 1ull;
      kept |= take << r;
      alive &= ~(take ? mr : 0ull);
    }
    // ---- record kept rows (wave 0 only; kept identical in all waves) ----
    if (wv == 0) {
      uint32_t below = (uint32_t)__popcll((unsigned long long)(kept & ((1ull << lane) - 1ull)));
      if ((kept >> lane) & 1ull) {
        uint32_t pos = (uint32_t)cnt + below;
        if (pos < 1088u) list[pos] = (uint32_t)(base + lane);
      }
    }
    cnt += (int)__popcll((unsigned long long)kept);   // uniform across waves
    if (cnt >= POST_K) break;                         // all waves break together
    if (g + 1 >= WORDS) break;
    // ---- fold this wave's 16 rows (drain happens here) ----
    uint64_t accA = 0, accB = 0;
    #pragma unroll
    for (int k = 0; k < RPW; k++) {
      uint64_t s = 0ull - ((kept >> (wv * RPW + k)) & 1ull);
      accA |= vA[k] & s;
      accB |= vB[k] & s;
    }
    rA |= accA;                                       // stale low words never re-read
    rB |= accB;
    // ---- publish partial removed word g+1 into the other buffer ----
    int nw = g + 1;
    if (lane == (nw >> 1)) remS[nw & 1][wv] = (nw & 1) ? rB : rA;
    __syncthreads();                                  // one barrier per group
  }
  __syncthreads();
  float4* outv = (float4*)out;
  for (int k = tid; k < POST_K; k += 256)
    outv[k] = (k < cnt) ? boxes[list[k]] : make_float4(0.f, 0.f, 0.f, 0.f);
}

extern "C" void kernel_launch(void* const* d_in, const int* in_sizes, int n_in,
                              void* d_out, int out_size, void* d_ws, size_t ws_size,
                              hipStream_t stream) {
  const float4* anchors = (const float4*)d_in[1];
  const float4* deltas  = (const float4*)d_in[2];
  const float*  logits  = (const float*)d_in[3];
  char* w = (char*)d_ws;
  uint32_t* keys  = (uint32_t*)(w + OFF_KEYS);
  uint32_t* hist1 = (uint32_t*)(w + OFF_HIST1);
  uint32_t* hist2 = (uint32_t*)(w + OFF_HIST2);
  uint32_t* ctrl  = (uint32_t*)(w + OFF_CTRL);
  uint64_t* cand  = (uint64_t*)(w + OFF_CAND);
  float4*   boxes = (float4*)(w + OFF_BOXES);
  uint32_t* valid = (uint32_t*)(w + OFF_VALID);
  uint64_t* mask  = (uint64_t*)(w + OFF_MASK);
  float*    out   = (float*)d_out;

  hipMemsetAsync(w + OFF_HIST1, 0, 0x4400, stream);  // hist1 (16K) + hist2 (1K)
  hipMemsetAsync(w + OFF_CTRL, 0, 256, stream);      // counters only

  k_decode<<<(N_ANCH + 255) / 256, 256, 0, stream>>>(anchors, deltas, logits, keys);
  k_histA<<<NBLK4, 1024, 0, stream>>>((const uint4*)keys, hist1);
  k_cut1<<<1, 1024, 0, stream>>>(hist1, ctrl);
  k_hist2<<<NBLK256, 256, 0, stream>>>((const uint4*)keys, ctrl, hist2);
  k_cut2<<<1, 64, 0, stream>>>(hist2, ctrl);
  k_compact<<<NBLK256, 256, 0, stream>>>((const uint4*)keys, logits, ctrl, cand);
  k_rank<<<RBLK, 256, 0, stream>>>(ctrl, cand, anchors, deltas, boxes, valid);
  k_iou<<<dim3(WORDS, WORDS), 64, 0, stream>>>(boxes, mask);
  k_nms<<<1, 256, 0, stream>>>(mask, boxes, valid, out);
}